// Round 1
// baseline (800.452 us; speedup 1.0000x reference)
//
#include <hip/hip_runtime.h>

#define NN 100000
#define EE 600000
#define GG 512
#define HH 128
#define IND 74      // 60 + 2 + 12
#define S0 76       // padded stride for h0 / agg0
#define LN_EPS 1e-5f

// ---------------- assemble h0 = [x | xdims | emb[xsttype]] ----------------
__global__ __launch_bounds__(256) void assemble_kernel(
    const float* __restrict__ x, const float* __restrict__ xdims,
    const int* __restrict__ stt, const float* __restrict__ emb,
    float* __restrict__ h0)
{
    int idx = blockIdx.x * 256 + threadIdx.x;
    if (idx >= NN * S0) return;
    int n = idx / S0, c = idx - n * S0;
    float v;
    if (c < 60)       v = x[n * 60 + c];
    else if (c < 62)  v = xdims[n * 2 + (c - 60)];
    else if (c < 74)  v = emb[stt[n] * 12 + (c - 62)];
    else              v = 0.0f;
    h0[idx] = v;
}

// ---------------- degree count ----------------
__global__ __launch_bounds__(256) void count_deg_kernel(
    const int* __restrict__ ei, int* __restrict__ deg)
{
    int e = blockIdx.x * 256 + threadIdx.x;
    if (e >= EE) return;
    atomicAdd(&deg[ei[EE + e]], 1);
}

// ---------------- exclusive scan of deg -> offs (3 kernels) ----------------
__global__ __launch_bounds__(256) void scan1_kernel(
    const int* __restrict__ deg, int* __restrict__ offs, int* __restrict__ bsum)
{
    __shared__ int ts[256];
    int t = threadIdx.x;
    int base = blockIdx.x * 2048 + t * 8;
    int d[8];
    if (base + 8 <= NN) {
        int4 a = *(const int4*)&deg[base];
        int4 b = *(const int4*)&deg[base + 4];
        d[0]=a.x; d[1]=a.y; d[2]=a.z; d[3]=a.w;
        d[4]=b.x; d[5]=b.y; d[6]=b.z; d[7]=b.w;
    } else {
        #pragma unroll
        for (int i = 0; i < 8; ++i) d[i] = (base + i < NN) ? deg[base + i] : 0;
    }
    int e[8]; int run = 0;
    #pragma unroll
    for (int i = 0; i < 8; ++i) { e[i] = run; run += d[i]; }
    ts[t] = run;
    int tot = run;
    __syncthreads();
    for (int off = 1; off < 256; off <<= 1) {
        int u = (t >= off) ? ts[t - off] : 0;
        __syncthreads();
        ts[t] += u;
        __syncthreads();
    }
    int pre = ts[t] - tot;
    if (base + 8 <= NN) {
        *(int4*)&offs[base]     = make_int4(e[0]+pre, e[1]+pre, e[2]+pre, e[3]+pre);
        *(int4*)&offs[base + 4] = make_int4(e[4]+pre, e[5]+pre, e[6]+pre, e[7]+pre);
    } else {
        #pragma unroll
        for (int i = 0; i < 8; ++i) if (base + i < NN) offs[base + i] = e[i] + pre;
    }
    if (t == 255) bsum[blockIdx.x] = ts[255];
}

__global__ void scan2_kernel(int* __restrict__ bsum, int nb)
{
    int t = threadIdx.x;   // 64 threads, one wave
    int v = (t < nb) ? bsum[t] : 0;
    int inc = v;
    for (int off = 1; off < 64; off <<= 1) {
        int u = __shfl_up(inc, off, 64);
        if (t >= off) inc += u;
    }
    if (t < nb) bsum[t] = inc - v;   // exclusive
}

__global__ __launch_bounds__(256) void scan3_kernel(
    int* __restrict__ offs, const int* __restrict__ bsum,
    const int* __restrict__ deg, float* __restrict__ invdeg)
{
    int i = blockIdx.x * 256 + threadIdx.x;
    if (i >= NN) return;
    offs[i] += bsum[i / 2048];
    int d = deg[i];
    invdeg[i] = 1.0f / (float)(d > 1 ? d : 1);
}

// ---------------- CSR fill ----------------
__global__ __launch_bounds__(256) void fill_csr_kernel(
    const int* __restrict__ ei, int* __restrict__ cur,
    const int* __restrict__ offs, int* __restrict__ csr)
{
    int e = blockIdx.x * 256 + threadIdx.x;
    if (e >= EE) return;
    int d = ei[EE + e];
    int p = offs[d] + atomicAdd(&cur[d], 1);
    csr[p] = ei[e];
}

// ---------------- mean aggregation (gather over CSR) ----------------
__global__ __launch_bounds__(256) void agg_gather_kernel(
    const float* __restrict__ Hin, int sIn, int F,
    const int* __restrict__ csr, const int* __restrict__ offs,
    const int* __restrict__ deg, const float* __restrict__ invdeg,
    float* __restrict__ Aout, int sOut)
{
    int n = blockIdx.x * 2 + (threadIdx.x >> 7);
    int j = threadIdx.x & 127;
    if (n >= NN) return;
    int st = offs[n], d = deg[n];
    float s = 0.0f;
    for (int e = 0; e < d; ++e) {
        int srcn = csr[st + e];
        if (j < F) s += Hin[(size_t)srcn * sIn + j];
    }
    if (j < F) Aout[(size_t)n * sOut + j] = s * invdeg[n];
}

// ---------------- fused dual-GEMM + LayerNorm + ReLU ----------------
// Out[n][j] = LN( A1[n]@W1 + bias + A2[n]@W2 )[j], relu'd.  128 outputs.
__global__ __launch_bounds__(256) void gemm_ln_kernel(
    const float* __restrict__ A1, int sA1, int K1,
    const float* __restrict__ A2, int sA2, int K2,
    const float* __restrict__ W1, const float* __restrict__ W2,
    const float* __restrict__ bias, const float* __restrict__ gamma,
    const float* __restrict__ beta, float* __restrict__ Out)
{
    __shared__ float Asm[256][36];    // [k][node], padded to 36 for b128-aligned rows
    __shared__ float Wsm[16][128];
    const int K = K1 + K2;
    const int tid = threadIdx.x;
    const int n0 = blockIdx.x * 32;

    // stage A transposed: coalesced global reads (consecutive tid -> consecutive k)
    const int tot = K * 32;
    for (int idx = tid; idx < tot; idx += 256) {
        int k = idx % K;
        int n = idx / K;
        float v = (k < K1) ? A1[(size_t)(n0 + n) * sA1 + k]
                           : A2[(size_t)(n0 + n) * sA2 + (k - K1)];
        Asm[k][n] = v;
    }

    const int tx = tid & 31, ty = tid >> 5;
    const int j0 = tx * 4, m0 = ty * 4;
    float acc[4][4];
    {
        float b0 = bias[j0], b1 = bias[j0+1], b2 = bias[j0+2], b3 = bias[j0+3];
        #pragma unroll
        for (int ni = 0; ni < 4; ++ni) {
            acc[ni][0] = b0; acc[ni][1] = b1; acc[ni][2] = b2; acc[ni][3] = b3;
        }
    }

    for (int kc0 = 0; kc0 < K; kc0 += 16) {
        int kcn = min(16, K - kc0);
        for (int idx = tid; idx < kcn * 128; idx += 256) {
            int kl = idx >> 7, j = idx & 127;
            int k = kc0 + kl;
            Wsm[kl][j] = (k < K1) ? W1[k * HH + j] : W2[(k - K1) * HH + j];
        }
        __syncthreads();
        for (int kk = 0; kk < kcn; ++kk) {
            float4 av = *(const float4*)&Asm[kc0 + kk][m0];
            float4 wv = *(const float4*)&Wsm[kk][j0];
            float aa[4] = {av.x, av.y, av.z, av.w};
            float ww[4] = {wv.x, wv.y, wv.z, wv.w};
            #pragma unroll
            for (int ni = 0; ni < 4; ++ni)
                #pragma unroll
                for (int ji = 0; ji < 4; ++ji)
                    acc[ni][ji] = fmaf(aa[ni], ww[ji], acc[ni][ji]);
        }
        __syncthreads();
    }

    // LayerNorm across 128 features of each node: reduce over the 32 tx-lanes
    // (they are one half of a wave64, xor masks <32 stay inside the half)
    float g4[4] = {gamma[j0], gamma[j0+1], gamma[j0+2], gamma[j0+3]};
    float b4[4] = {beta[j0],  beta[j0+1],  beta[j0+2],  beta[j0+3]};
    #pragma unroll
    for (int ni = 0; ni < 4; ++ni) {
        float s = 0.0f, q = 0.0f;
        #pragma unroll
        for (int ji = 0; ji < 4; ++ji) {
            float h = acc[ni][ji];
            s += h; q += h * h;
        }
        #pragma unroll
        for (int off = 16; off > 0; off >>= 1) {
            s += __shfl_xor(s, off, 64);
            q += __shfl_xor(q, off, 64);
        }
        float mu  = s * (1.0f / 128.0f);
        float var = q * (1.0f / 128.0f) - mu * mu;
        float r   = rsqrtf(var + LN_EPS);
        float4 o;
        o.x = fmaxf(0.0f, (acc[ni][0] - mu) * r * g4[0] + b4[0]);
        o.y = fmaxf(0.0f, (acc[ni][1] - mu) * r * g4[1] + b4[1]);
        o.z = fmaxf(0.0f, (acc[ni][2] - mu) * r * g4[2] + b4[2]);
        o.w = fmaxf(0.0f, (acc[ni][3] - mu) * r * g4[3] + b4[3]);
        *(float4*)&Out[(size_t)(n0 + m0 + ni) * HH + j0] = o;
    }
}

// ---------------- graph pooling (batch is sorted) ----------------
__global__ __launch_bounds__(128) void pool_kernel(
    const float* __restrict__ H, const int* __restrict__ batch,
    float* __restrict__ psum, int* __restrict__ pmax, int* __restrict__ cnt)
{
    int j = threadIdx.x;                 // 128 features
    int nbeg = blockIdx.x * 128;
    int nend = nbeg + 128; if (nend > NN) nend = NN;
    if (nbeg >= NN) return;
    int curg = batch[nbeg];
    float s = 0.0f, m = 0.0f;
    int c = 0;
    for (int n = nbeg; n < nend; ++n) {
        int g = batch[n];
        if (g != curg) {
            atomicAdd(&psum[curg * HH + j], s);
            atomicMax(&pmax[curg * HH + j], __float_as_int(m));
            if (j == 0) atomicAdd(&cnt[curg], c);
            s = 0.0f; m = 0.0f; c = 0; curg = g;
        }
        float v = H[(size_t)n * HH + j];
        s += v; m = fmaxf(m, v); ++c;
    }
    atomicAdd(&psum[curg * HH + j], s);
    atomicMax(&pmax[curg * HH + j], __float_as_int(m));
    if (j == 0) atomicAdd(&cnt[curg], c);
}

// ---------------- final MLP (one block per graph) ----------------
__global__ __launch_bounds__(64) void mlp_kernel(
    const float* __restrict__ psum, const int* __restrict__ pmax,
    const int* __restrict__ cnt,
    const float* __restrict__ Wf0, const float* __restrict__ bf0,
    const float* __restrict__ Wf1, const float* __restrict__ bf1,
    const float* __restrict__ Wf2, const float* __restrict__ bf2,
    float* __restrict__ out)
{
    __shared__ float z[256];
    __shared__ float t1[50];
    __shared__ float t2[50];
    int g = blockIdx.x, t = threadIdx.x;
    int c = cnt[g];
    float ic = 1.0f / (float)(c > 1 ? c : 1);
    for (int j = t; j < 128; j += 64) {
        z[j]       = psum[g * HH + j] * ic;
        z[128 + j] = __int_as_float(pmax[g * HH + j]);
    }
    __syncthreads();
    if (t < 50) {
        float a = bf0[t];
        for (int k = 0; k < 256; ++k) a = fmaf(z[k], Wf0[k * 50 + t], a);
        t1[t] = fmaxf(a, 0.0f);
    }
    __syncthreads();
    if (t < 50) {
        float a = bf1[t];
        for (int k = 0; k < 50; ++k) a = fmaf(t1[k], Wf1[k * 50 + t], a);
        t2[t] = fmaxf(a, 0.0f);
    }
    __syncthreads();
    if (t < 10) {
        float a = bf2[t];
        for (int k = 0; k < 50; ++k) a = fmaf(t2[k], Wf2[k * 10 + t], a);
        out[g * 10 + t] = fmaxf(a, 0.0f);
    }
}

// ---------------- launcher ----------------
extern "C" void kernel_launch(void* const* d_in, const int* in_sizes, int n_in,
                              void* d_out, int out_size, void* d_ws, size_t ws_size,
                              hipStream_t stream)
{
    const float* x     = (const float*)d_in[0];
    const float* xdims = (const float*)d_in[1];
    const int*   stt   = (const int*)d_in[2];
    const int*   ei    = (const int*)d_in[3];
    const int*   batch = (const int*)d_in[4];
    const float* emb   = (const float*)d_in[5];
    const float* Wl0   = (const float*)d_in[6];
    const float* bl0   = (const float*)d_in[7];
    const float* Wr0   = (const float*)d_in[8];
    const float* g0    = (const float*)d_in[9];
    const float* bn0   = (const float*)d_in[10];
    const float* Wl1   = (const float*)d_in[11];
    const float* bl1   = (const float*)d_in[12];
    const float* Wr1   = (const float*)d_in[13];
    const float* g1    = (const float*)d_in[14];
    const float* bn1   = (const float*)d_in[15];
    const float* Wf0   = (const float*)d_in[16];
    const float* bf0   = (const float*)d_in[17];
    const float* Wf1   = (const float*)d_in[18];
    const float* bf1   = (const float*)d_in[19];
    const float* Wf2   = (const float*)d_in[20];
    const float* bf2   = (const float*)d_in[21];

    char* w = (char*)d_ws;
    float* h0   = (float*)w; w += (size_t)NN * S0 * 4;
    float* bufA = (float*)w; w += (size_t)NN * HH * 4;
    float* bufB = (float*)w; w += (size_t)NN * HH * 4;
    int*   csr  = (int*)w;   w += (size_t)EE * 4;
    int*   offs = (int*)w;   w += (size_t)NN * 4;
    float* invdeg = (float*)w; w += (size_t)NN * 4;
    int*   bsum = (int*)w;   w += 256 * 4;
    // zeroed region (one memset):
    char* zbeg = w;
    int*   deg  = (int*)w;   w += (size_t)NN * 4;
    int*   cur  = (int*)w;   w += (size_t)NN * 4;
    int*   cnt  = (int*)w;   w += (size_t)GG * 4;
    float* psum = (float*)w; w += (size_t)GG * HH * 4;
    int*   pmax = (int*)w;   w += (size_t)GG * HH * 4;
    size_t zsz = (size_t)(w - zbeg);

    hipMemsetAsync(zbeg, 0, zsz, stream);

    assemble_kernel<<<(NN * S0 + 255) / 256, 256, 0, stream>>>(x, xdims, stt, emb, h0);
    count_deg_kernel<<<(EE + 255) / 256, 256, 0, stream>>>(ei, deg);
    int nb = (NN + 2047) / 2048;
    scan1_kernel<<<nb, 256, 0, stream>>>(deg, offs, bsum);
    scan2_kernel<<<1, 64, 0, stream>>>(bsum, nb);
    scan3_kernel<<<(NN + 255) / 256, 256, 0, stream>>>(offs, bsum, deg, invdeg);
    fill_csr_kernel<<<(EE + 255) / 256, 256, 0, stream>>>(ei, cur, offs, csr);

    // layer 0
    agg_gather_kernel<<<(NN + 1) / 2, 256, 0, stream>>>(h0, S0, IND, csr, offs, deg, invdeg, bufB, S0);
    gemm_ln_kernel<<<NN / 32, 256, 0, stream>>>(bufB, S0, IND, h0, S0, IND,
                                                Wl0, Wr0, bl0, g0, bn0, bufA);
    // layer 1
    agg_gather_kernel<<<(NN + 1) / 2, 256, 0, stream>>>(bufA, HH, HH, csr, offs, deg, invdeg, bufB, HH);
    gemm_ln_kernel<<<NN / 32, 256, 0, stream>>>(bufB, HH, HH, bufA, HH, HH,
                                                Wl1, Wr1, bl1, g1, bn1, bufA);

    pool_kernel<<<(NN + 127) / 128, 128, 0, stream>>>(bufA, batch, psum, pmax, cnt);
    mlp_kernel<<<GG, 64, 0, stream>>>(psum, pmax, cnt, Wf0, bf0, Wf1, bf1, Wf2, bf2,
                                      (float*)d_out);
}

// Round 2
// 391.469 us; speedup vs baseline: 2.0447x; 2.0447x over previous
//
#include <hip/hip_runtime.h>

#define NN 100000
#define NP 100096          // padded to multiple of 64
#define EE 600000
#define GG 512
#define LN_EPS 1e-5f

typedef __attribute__((ext_vector_type(8))) __bf16 bf16x8;
typedef __attribute__((ext_vector_type(4))) float f32x4;

__device__ __forceinline__ float bf2f(unsigned short u) {
    return __uint_as_float(((unsigned int)u) << 16);
}
__device__ __forceinline__ unsigned short f2bf(float f) {
    unsigned int u = __float_as_uint(f);
    u = (u + 0x7fffu + ((u >> 16) & 1u)) >> 16;
    return (unsigned short)u;
}
__device__ __forceinline__ unsigned int pack2(float a, float b) {
    return (unsigned int)f2bf(a) | ((unsigned int)f2bf(b) << 16);
}

// ---------------- assemble h0 (bf16) into A0 cols 80..159 ----------------
// A0 row: [0..79] = agg0 (written later), [80..153] = h0, [154..159] = 0 pad
__global__ __launch_bounds__(256) void assemble_kernel(
    const float* __restrict__ x, const float* __restrict__ xdims,
    const int* __restrict__ stt, const float* __restrict__ emb,
    unsigned short* __restrict__ A0)
{
    int idx = blockIdx.x * 256 + threadIdx.x;   // over NP*80
    int n = idx / 80, c = idx - n * 80;
    if (n >= NP) return;
    float v = 0.f;
    if (n < NN) {
        if (c < 60)      v = x[n * 60 + c];
        else if (c < 62) v = xdims[n * 2 + (c - 60)];
        else if (c < 74) v = emb[stt[n] * 12 + (c - 62)];
    }
    A0[(size_t)n * 160 + 80 + c] = f2bf(v);
}

// ---------------- weight transpose+pad to bf16 Wt[n][k] ----------------
__global__ __launch_bounds__(256) void wtprep0_kernel(
    const float* __restrict__ Wl, const float* __restrict__ Wr,
    unsigned short* __restrict__ Wt)
{
    int idx = blockIdx.x * 256 + threadIdx.x;   // 128*160
    int n = idx / 160, k = idx - n * 160;
    float v = 0.f;
    if (k < 74)                  v = Wl[k * 128 + n];
    else if (k >= 80 && k < 154) v = Wr[(k - 80) * 128 + n];
    Wt[(size_t)n * 160 + k] = f2bf(v);
}
__global__ __launch_bounds__(256) void wtprep1_kernel(
    const float* __restrict__ Wl, const float* __restrict__ Wr,
    unsigned short* __restrict__ Wt)
{
    int idx = blockIdx.x * 256 + threadIdx.x;   // 128*256
    int n = idx >> 8, k = idx & 255;
    float v = (k < 128) ? Wl[k * 128 + n] : Wr[(k - 128) * 128 + n];
    Wt[(size_t)n * 256 + k] = f2bf(v);
}

// ---------------- degree count ----------------
__global__ __launch_bounds__(256) void count_deg_kernel(
    const int* __restrict__ ei, int* __restrict__ deg)
{
    int e = blockIdx.x * 256 + threadIdx.x;
    if (e >= EE) return;
    atomicAdd(&deg[ei[EE + e]], 1);
}

// ---------------- exclusive scan of deg -> offs ----------------
__global__ __launch_bounds__(256) void scan1_kernel(
    const int* __restrict__ deg, int* __restrict__ offs, int* __restrict__ bsum)
{
    __shared__ int ts[256];
    int t = threadIdx.x;
    int base = blockIdx.x * 2048 + t * 8;
    int d[8];
    if (base + 8 <= NN) {
        int4 a = *(const int4*)&deg[base];
        int4 b = *(const int4*)&deg[base + 4];
        d[0]=a.x; d[1]=a.y; d[2]=a.z; d[3]=a.w;
        d[4]=b.x; d[5]=b.y; d[6]=b.z; d[7]=b.w;
    } else {
        #pragma unroll
        for (int i = 0; i < 8; ++i) d[i] = (base + i < NN) ? deg[base + i] : 0;
    }
    int e[8]; int run = 0;
    #pragma unroll
    for (int i = 0; i < 8; ++i) { e[i] = run; run += d[i]; }
    ts[t] = run;
    int tot = run;
    __syncthreads();
    for (int off = 1; off < 256; off <<= 1) {
        int u = (t >= off) ? ts[t - off] : 0;
        __syncthreads();
        ts[t] += u;
        __syncthreads();
    }
    int pre = ts[t] - tot;
    #pragma unroll
    for (int i = 0; i < 8; ++i) if (base + i < NN) offs[base + i] = e[i] + pre;
    if (t == 255) bsum[blockIdx.x] = ts[255];
}

__global__ void scan2_kernel(int* __restrict__ bsum, int nb)
{
    int t = threadIdx.x;   // 64 threads, one wave
    int v = (t < nb) ? bsum[t] : 0;
    int inc = v;
    for (int off = 1; off < 64; off <<= 1) {
        int u = __shfl_up(inc, off, 64);
        if (t >= off) inc += u;
    }
    if (t < nb) bsum[t] = inc - v;   // exclusive
}

__global__ __launch_bounds__(256) void scan3_kernel(
    int* __restrict__ offs, const int* __restrict__ bsum,
    const int* __restrict__ deg, float* __restrict__ invdeg)
{
    int i = blockIdx.x * 256 + threadIdx.x;
    if (i >= NN) return;
    offs[i] += bsum[i / 2048];
    int d = deg[i];
    invdeg[i] = 1.0f / (float)(d > 1 ? d : 1);
}

// ---------------- CSR fill ----------------
__global__ __launch_bounds__(256) void fill_csr_kernel(
    const int* __restrict__ ei, int* __restrict__ cur,
    const int* __restrict__ offs, int* __restrict__ csr)
{
    int e = blockIdx.x * 256 + threadIdx.x;
    if (e >= EE) return;
    int d = ei[EE + e];
    int p = offs[d] + atomicAdd(&cur[d], 1);
    csr[p] = ei[e];
}

// ---------------- mean aggregation layer0: gather A0 cols 80..159 -> cols 0..79 ----------------
__global__ __launch_bounds__(256) void agg0_kernel(
    unsigned short* __restrict__ A0, const int* __restrict__ csr,
    const int* __restrict__ offs, const int* __restrict__ deg,
    const float* __restrict__ invdeg)
{
    int node = blockIdx.x * 8 + (threadIdx.x >> 5);
    int lane = threadIdx.x & 31;
    if (node >= NP || lane >= 20) return;
    int d = 0, st = 0; float iv = 0.f;
    if (node < NN) { d = deg[node]; st = offs[node]; iv = invdeg[node]; }
    float s0=0.f, s1=0.f, s2=0.f, s3=0.f;
    int e = 0;
    for (; e + 2 <= d; e += 2) {
        int i0 = csr[st + e], i1 = csr[st + e + 1];
        ushort4 v0 = *(const ushort4*)(A0 + (size_t)i0 * 160 + 80 + lane * 4);
        ushort4 v1 = *(const ushort4*)(A0 + (size_t)i1 * 160 + 80 + lane * 4);
        s0 += bf2f(v0.x) + bf2f(v1.x);
        s1 += bf2f(v0.y) + bf2f(v1.y);
        s2 += bf2f(v0.z) + bf2f(v1.z);
        s3 += bf2f(v0.w) + bf2f(v1.w);
    }
    if (e < d) {
        int i0 = csr[st + e];
        ushort4 v0 = *(const ushort4*)(A0 + (size_t)i0 * 160 + 80 + lane * 4);
        s0 += bf2f(v0.x); s1 += bf2f(v0.y); s2 += bf2f(v0.z); s3 += bf2f(v0.w);
    }
    ushort4 o;
    o.x = f2bf(s0 * iv); o.y = f2bf(s1 * iv); o.z = f2bf(s2 * iv); o.w = f2bf(s3 * iv);
    *(ushort4*)(A0 + (size_t)node * 160 + lane * 4) = o;
}

// ---------------- mean aggregation layer1: gather A1 cols 128..255 -> cols 0..127 ----------------
__global__ __launch_bounds__(256) void agg1_kernel(
    unsigned short* __restrict__ A1, const int* __restrict__ csr,
    const int* __restrict__ offs, const int* __restrict__ deg,
    const float* __restrict__ invdeg)
{
    int node = blockIdx.x * 16 + (threadIdx.x >> 4);
    int lane = threadIdx.x & 15;
    if (node >= NP) return;
    int d = 0, st = 0; float iv = 0.f;
    if (node < NN) { d = deg[node]; st = offs[node]; iv = invdeg[node]; }
    float s[8];
    #pragma unroll
    for (int i = 0; i < 8; ++i) s[i] = 0.f;
    int e = 0;
    for (; e + 2 <= d; e += 2) {
        int i0 = csr[st + e], i1 = csr[st + e + 1];
        uint4 v0 = *(const uint4*)(A1 + (size_t)i0 * 256 + 128 + lane * 8);
        uint4 v1 = *(const uint4*)(A1 + (size_t)i1 * 256 + 128 + lane * 8);
        s[0] += __uint_as_float(v0.x << 16) + __uint_as_float(v1.x << 16);
        s[1] += __uint_as_float(v0.x & 0xffff0000u) + __uint_as_float(v1.x & 0xffff0000u);
        s[2] += __uint_as_float(v0.y << 16) + __uint_as_float(v1.y << 16);
        s[3] += __uint_as_float(v0.y & 0xffff0000u) + __uint_as_float(v1.y & 0xffff0000u);
        s[4] += __uint_as_float(v0.z << 16) + __uint_as_float(v1.z << 16);
        s[5] += __uint_as_float(v0.z & 0xffff0000u) + __uint_as_float(v1.z & 0xffff0000u);
        s[6] += __uint_as_float(v0.w << 16) + __uint_as_float(v1.w << 16);
        s[7] += __uint_as_float(v0.w & 0xffff0000u) + __uint_as_float(v1.w & 0xffff0000u);
    }
    if (e < d) {
        int i0 = csr[st + e];
        uint4 v0 = *(const uint4*)(A1 + (size_t)i0 * 256 + 128 + lane * 8);
        s[0] += __uint_as_float(v0.x << 16);
        s[1] += __uint_as_float(v0.x & 0xffff0000u);
        s[2] += __uint_as_float(v0.y << 16);
        s[3] += __uint_as_float(v0.y & 0xffff0000u);
        s[4] += __uint_as_float(v0.z << 16);
        s[5] += __uint_as_float(v0.z & 0xffff0000u);
        s[6] += __uint_as_float(v0.w << 16);
        s[7] += __uint_as_float(v0.w & 0xffff0000u);
    }
    uint4 o;
    o.x = pack2(s[0] * iv, s[1] * iv);
    o.y = pack2(s[2] * iv, s[3] * iv);
    o.z = pack2(s[4] * iv, s[5] * iv);
    o.w = pack2(s[6] * iv, s[7] * iv);
    *(uint4*)(A1 + (size_t)node * 256 + lane * 8) = o;
}

// ---------------- MFMA GEMM + LayerNorm + ReLU ----------------
// C[node][j] = relu(LN(A[node][:] @ Wt[j][:] + bias[j]))
// block = 256 thr = 4 waves; wave w: 16 nodes (n0+w*16..+15) x 128 cols
// C/D layout: col = lane&15, row = (lane>>4)*4 + reg   [m89]
// A-frag:     m  = lane&15, k = (lane>>4)*8 + j        [m120]
template<int K, int KT, int AS, bool OUTF>
__global__ __launch_bounds__(256) void gemm_mfma_ln_kernel(
    const unsigned short* __restrict__ A,
    const unsigned short* __restrict__ Wt,
    const float* __restrict__ bias, const float* __restrict__ gamma,
    const float* __restrict__ beta,
    unsigned short* __restrict__ outB, float* __restrict__ outF)
{
    __shared__ unsigned short Asm[64 * AS];   // AS: 16B-aligned rows, stride/4 words ~odd pattern
    const int tid = threadIdx.x;
    const int n0 = blockIdx.x * 64;
    constexpr int CPR = K / 8;
    for (int i = tid; i < 64 * CPR; i += 256) {
        int node = i / CPR, c = i - node * CPR;
        uint4 v = *(const uint4*)(A + (size_t)(n0 + node) * K + c * 8);
        *(uint4*)(Asm + node * AS + c * 8) = v;
    }
    __syncthreads();

    const int l = tid & 63, w = tid >> 6;
    const int g = l >> 4, c0 = l & 15;
    const unsigned short* arow = Asm + (w * 16 + c0) * AS + g * 8;
    const unsigned short* brow = Wt + (size_t)c0 * K + g * 8;

    f32x4 acc[8];
    #pragma unroll
    for (int nt = 0; nt < 8; ++nt) acc[nt] = (f32x4){0.f, 0.f, 0.f, 0.f};

    #pragma unroll
    for (int kt = 0; kt < KT; ++kt) {
        bf16x8 a = *(const bf16x8*)(arow + kt * 32);
        #pragma unroll
        for (int nt = 0; nt < 8; ++nt) {
            bf16x8 b = *(const bf16x8*)(brow + (size_t)nt * 16 * K + kt * 32);
            acc[nt] = __builtin_amdgcn_mfma_f32_16x16x32_bf16(a, b, acc[nt], 0, 0, 0);
        }
    }

    float b8[8], g8[8], e8[8];
    #pragma unroll
    for (int nt = 0; nt < 8; ++nt) {
        int cc = nt * 16 + c0;
        b8[nt] = bias[cc]; g8[nt] = gamma[cc]; e8[nt] = beta[cc];
    }
    #pragma unroll
    for (int r = 0; r < 4; ++r) {
        int node = n0 + w * 16 + g * 4 + r;
        float s = 0.f, q = 0.f;
        #pragma unroll
        for (int nt = 0; nt < 8; ++nt) {
            float h = acc[nt][r] + b8[nt];
            s += h; q += h * h;
        }
        #pragma unroll
        for (int m = 1; m < 16; m <<= 1) {
            s += __shfl_xor(s, m, 64);
            q += __shfl_xor(q, m, 64);
        }
        float mu   = s * (1.f / 128.f);
        float var  = q * (1.f / 128.f) - mu * mu;
        float rinv = rsqrtf(var + LN_EPS);
        #pragma unroll
        for (int nt = 0; nt < 8; ++nt) {
            float h = acc[nt][r] + b8[nt];
            float v = fmaxf(0.f, (h - mu) * rinv * g8[nt] + e8[nt]);
            if (OUTF) outF[(size_t)node * 128 + nt * 16 + c0] = v;
            else      outB[(size_t)node * 256 + 128 + nt * 16 + c0] = f2bf(v);
        }
    }
}

// ---------------- graph pooling (batch is sorted) ----------------
__global__ __launch_bounds__(128) void pool_kernel(
    const float* __restrict__ H, const int* __restrict__ batch,
    float* __restrict__ psum, int* __restrict__ pmax, int* __restrict__ cnt)
{
    int j = threadIdx.x;                 // 128 features
    int nbeg = blockIdx.x * 128;
    int nend = nbeg + 128; if (nend > NN) nend = NN;
    if (nbeg >= NN) return;
    int curg = batch[nbeg];
    float s = 0.0f, m = 0.0f;
    int c = 0;
    for (int n = nbeg; n < nend; ++n) {
        int g = batch[n];
        if (g != curg) {
            atomicAdd(&psum[curg * 128 + j], s);
            atomicMax(&pmax[curg * 128 + j], __float_as_int(m));
            if (j == 0) atomicAdd(&cnt[curg], c);
            s = 0.0f; m = 0.0f; c = 0; curg = g;
        }
        float v = H[(size_t)n * 128 + j];
        s += v; m = fmaxf(m, v); ++c;
    }
    atomicAdd(&psum[curg * 128 + j], s);
    atomicMax(&pmax[curg * 128 + j], __float_as_int(m));
    if (j == 0) atomicAdd(&cnt[curg], c);
}

// ---------------- final MLP (one block per graph) ----------------
__global__ __launch_bounds__(64) void mlp_kernel(
    const float* __restrict__ psum, const int* __restrict__ pmax,
    const int* __restrict__ cnt,
    const float* __restrict__ Wf0, const float* __restrict__ bf0,
    const float* __restrict__ Wf1, const float* __restrict__ bf1,
    const float* __restrict__ Wf2, const float* __restrict__ bf2,
    float* __restrict__ out)
{
    __shared__ float z[256];
    __shared__ float t1[50];
    __shared__ float t2[50];
    int g = blockIdx.x, t = threadIdx.x;
    int c = cnt[g];
    float ic = 1.0f / (float)(c > 1 ? c : 1);
    for (int j = t; j < 128; j += 64) {
        z[j]       = psum[g * 128 + j] * ic;
        z[128 + j] = __int_as_float(pmax[g * 128 + j]);
    }
    __syncthreads();
    if (t < 50) {
        float a = bf0[t];
        for (int k = 0; k < 256; ++k) a = fmaf(z[k], Wf0[k * 50 + t], a);
        t1[t] = fmaxf(a, 0.0f);
    }
    __syncthreads();
    if (t < 50) {
        float a = bf1[t];
        for (int k = 0; k < 50; ++k) a = fmaf(t1[k], Wf1[k * 50 + t], a);
        t2[t] = fmaxf(a, 0.0f);
    }
    __syncthreads();
    if (t < 10) {
        float a = bf2[t];
        for (int k = 0; k < 50; ++k) a = fmaf(t2[k], Wf2[k * 10 + t], a);
        out[g * 10 + t] = fmaxf(a, 0.0f);
    }
}

// ---------------- launcher ----------------
extern "C" void kernel_launch(void* const* d_in, const int* in_sizes, int n_in,
                              void* d_out, int out_size, void* d_ws, size_t ws_size,
                              hipStream_t stream)
{
    const float* x     = (const float*)d_in[0];
    const float* xdims = (const float*)d_in[1];
    const int*   stt   = (const int*)d_in[2];
    const int*   ei    = (const int*)d_in[3];
    const int*   batch = (const int*)d_in[4];
    const float* emb   = (const float*)d_in[5];
    const float* Wl0   = (const float*)d_in[6];
    const float* bl0   = (const float*)d_in[7];
    const float* Wr0   = (const float*)d_in[8];
    const float* g0    = (const float*)d_in[9];
    const float* bn0   = (const float*)d_in[10];
    const float* Wl1   = (const float*)d_in[11];
    const float* bl1   = (const float*)d_in[12];
    const float* Wr1   = (const float*)d_in[13];
    const float* g1    = (const float*)d_in[14];
    const float* bn1   = (const float*)d_in[15];
    const float* Wf0   = (const float*)d_in[16];
    const float* bf0   = (const float*)d_in[17];
    const float* Wf1   = (const float*)d_in[18];
    const float* bf1   = (const float*)d_in[19];
    const float* Wf2   = (const float*)d_in[20];
    const float* bf2   = (const float*)d_in[21];

    char* w = (char*)d_ws;
    // region R1: A0 (bf16 [NP][160] = 32MB) early, H2 (f32 [NP][128] = 51.25MB) late.
    // A0 is dead once gemm0 has run; H2 is written by gemm1 (after gemm0). Safe alias.
    unsigned short* A0 = (unsigned short*)w;
    float*          H2 = (float*)w;          w += (size_t)NP * 128 * 4;
    unsigned short* A1 = (unsigned short*)w; w += (size_t)NP * 256 * 2;
    unsigned short* Wt0 = (unsigned short*)w; w += (size_t)128 * 160 * 2;
    unsigned short* Wt1 = (unsigned short*)w; w += (size_t)128 * 256 * 2;
    int*   csr  = (int*)w;   w += (size_t)EE * 4;
    int*   offs = (int*)w;   w += (size_t)NN * 4;
    float* invdeg = (float*)w; w += (size_t)NN * 4;
    int*   bsum = (int*)w;   w += 1024;
    // zeroed region (one memset):
    char* zbeg = w;
    int*   deg  = (int*)w;   w += (size_t)NP * 4;
    int*   cur  = (int*)w;   w += (size_t)NN * 4;
    int*   cnt  = (int*)w;   w += (size_t)GG * 4;
    float* psum = (float*)w; w += (size_t)GG * 128 * 4;
    int*   pmax = (int*)w;   w += (size_t)GG * 128 * 4;
    size_t zsz = (size_t)(w - zbeg);

    hipMemsetAsync(zbeg, 0, zsz, stream);

    wtprep0_kernel<<<(128 * 160 + 255) / 256, 256, 0, stream>>>(Wl0, Wr0, Wt0);
    wtprep1_kernel<<<(128 * 256) / 256, 256, 0, stream>>>(Wl1, Wr1, Wt1);
    assemble_kernel<<<(NP * 80) / 256, 256, 0, stream>>>(x, xdims, stt, emb, A0);

    count_deg_kernel<<<(EE + 255) / 256, 256, 0, stream>>>(ei, deg);
    int nb = (NN + 2047) / 2048;
    scan1_kernel<<<nb, 256, 0, stream>>>(deg, offs, bsum);
    scan2_kernel<<<1, 64, 0, stream>>>(bsum, nb);
    scan3_kernel<<<(NN + 255) / 256, 256, 0, stream>>>(offs, bsum, deg, invdeg);
    fill_csr_kernel<<<(EE + 255) / 256, 256, 0, stream>>>(ei, cur, offs, csr);

    // layer 0: agg h0 -> A0 cols 0..79; gemm -> h1 (bf16) into A1 cols 128..255
    agg0_kernel<<<NP / 8, 256, 0, stream>>>(A0, csr, offs, deg, invdeg);
    gemm_mfma_ln_kernel<160, 5, 168, false><<<NP / 64, 256, 0, stream>>>(
        A0, Wt0, bl0, g0, bn0, A1, nullptr);
    // layer 1: agg h1 -> A1 cols 0..127; gemm -> h2 (f32) into H2
    agg1_kernel<<<NP / 16, 256, 0, stream>>>(A1, csr, offs, deg, invdeg);
    gemm_mfma_ln_kernel<256, 8, 264, true><<<NP / 64, 256, 0, stream>>>(
        A1, Wt1, bl1, g1, bn1, nullptr, H2);

    pool_kernel<<<(NN + 127) / 128, 128, 0, stream>>>(H2, batch, psum, pmax, cnt);
    mlp_kernel<<<GG, 64, 0, stream>>>(psum, pmax, cnt, Wf0, bf0, Wf1, bf1, Wf2, bf2,
                                      (float*)d_out);
}

// Round 3
// 355.247 us; speedup vs baseline: 2.2532x; 1.1020x over previous
//
#include <hip/hip_runtime.h>

#define NN 100000
#define NP 100096          // padded to multiple of 64
#define EE 600000
#define GG 512
#define LN_EPS 1e-5f

typedef __attribute__((ext_vector_type(8))) __bf16 bf16x8;
typedef __attribute__((ext_vector_type(4))) float f32x4;

__device__ __forceinline__ float bf2f(unsigned short u) {
    return __uint_as_float(((unsigned int)u) << 16);
}
__device__ __forceinline__ unsigned short f2bf(float f) {
    unsigned int u = __float_as_uint(f);
    u = (u + 0x7fffu + ((u >> 16) & 1u)) >> 16;
    return (unsigned short)u;
}
__device__ __forceinline__ unsigned int pack2(float a, float b) {
    return (unsigned int)f2bf(a) | ((unsigned int)f2bf(b) << 16);
}

// ---------------- assemble h0 (bf16) into A0 cols 80..159 ----------------
// A0 row: [0..79] = agg0 (written later), [80..153] = h0, [154..159] = 0 pad
__global__ __launch_bounds__(256) void assemble_kernel(
    const float* __restrict__ x, const float* __restrict__ xdims,
    const int* __restrict__ stt, const float* __restrict__ emb,
    unsigned short* __restrict__ A0)
{
    int idx = blockIdx.x * 256 + threadIdx.x;   // over NP*80
    int n = idx / 80, c = idx - n * 80;
    if (n >= NP) return;
    float v = 0.f;
    if (n < NN) {
        if (c < 60)      v = x[n * 60 + c];
        else if (c < 62) v = xdims[n * 2 + (c - 60)];
        else if (c < 74) v = emb[stt[n] * 12 + (c - 62)];
    }
    A0[(size_t)n * 160 + 80 + c] = f2bf(v);
}

// ---------------- weight transpose+pad to bf16 Wt[n][k] (both layers) ----------------
__global__ __launch_bounds__(256) void wtprep_kernel(
    const float* __restrict__ Wl0, const float* __restrict__ Wr0,
    const float* __restrict__ Wl1, const float* __restrict__ Wr1,
    unsigned short* __restrict__ Wt0, unsigned short* __restrict__ Wt1)
{
    int idx = blockIdx.x * 256 + threadIdx.x;
    if (idx < 128 * 160) {
        int n = idx / 160, k = idx - n * 160;
        float v = 0.f;
        if (k < 74)                  v = Wl0[k * 128 + n];
        else if (k >= 80 && k < 154) v = Wr0[(k - 80) * 128 + n];
        Wt0[(size_t)n * 160 + k] = f2bf(v);
    } else if (idx < 128 * 160 + 128 * 256) {
        int j = idx - 128 * 160;
        int n = j >> 8, k = j & 255;
        float v = (k < 128) ? Wl1[k * 128 + n] : Wr1[(k - 128) * 128 + n];
        Wt1[(size_t)n * 256 + k] = f2bf(v);
    }
}

// ---------------- degree count ----------------
__global__ __launch_bounds__(256) void count_deg_kernel(
    const int* __restrict__ ei, int* __restrict__ deg)
{
    int e = blockIdx.x * 256 + threadIdx.x;
    if (e >= EE) return;
    atomicAdd(&deg[ei[EE + e]], 1);
}

// ---------------- exclusive scan of deg -> offs ----------------
__global__ __launch_bounds__(256) void scan1_kernel(
    const int* __restrict__ deg, int* __restrict__ offs, int* __restrict__ bsum)
{
    __shared__ int ts[256];
    int t = threadIdx.x;
    int base = blockIdx.x * 2048 + t * 8;
    int d[8];
    if (base + 8 <= NN) {
        int4 a = *(const int4*)&deg[base];
        int4 b = *(const int4*)&deg[base + 4];
        d[0]=a.x; d[1]=a.y; d[2]=a.z; d[3]=a.w;
        d[4]=b.x; d[5]=b.y; d[6]=b.z; d[7]=b.w;
    } else {
        #pragma unroll
        for (int i = 0; i < 8; ++i) d[i] = (base + i < NN) ? deg[base + i] : 0;
    }
    int e[8]; int run = 0;
    #pragma unroll
    for (int i = 0; i < 8; ++i) { e[i] = run; run += d[i]; }
    ts[t] = run;
    int tot = run;
    __syncthreads();
    for (int off = 1; off < 256; off <<= 1) {
        int u = (t >= off) ? ts[t - off] : 0;
        __syncthreads();
        ts[t] += u;
        __syncthreads();
    }
    int pre = ts[t] - tot;
    #pragma unroll
    for (int i = 0; i < 8; ++i) if (base + i < NN) offs[base + i] = e[i] + pre;
    if (t == 255) bsum[blockIdx.x] = ts[255];
}

__global__ void scan2_kernel(int* __restrict__ bsum, int nb)
{
    int t = threadIdx.x;   // 64 threads, one wave
    int v = (t < nb) ? bsum[t] : 0;
    int inc = v;
    for (int off = 1; off < 64; off <<= 1) {
        int u = __shfl_up(inc, off, 64);
        if (t >= off) inc += u;
    }
    if (t < nb) bsum[t] = inc - v;   // exclusive
}

__global__ __launch_bounds__(256) void scan3_kernel(
    int* __restrict__ offs, const int* __restrict__ bsum,
    const int* __restrict__ deg, float* __restrict__ invdeg)
{
    int i = blockIdx.x * 256 + threadIdx.x;
    if (i >= NN) return;
    offs[i] += bsum[i / 2048];
    int d = deg[i];
    invdeg[i] = 1.0f / (float)(d > 1 ? d : 1);
}

// ---------------- CSR fill ----------------
__global__ __launch_bounds__(256) void fill_csr_kernel(
    const int* __restrict__ ei, int* __restrict__ cur,
    const int* __restrict__ offs, int* __restrict__ csr)
{
    int e = blockIdx.x * 256 + threadIdx.x;
    if (e >= EE) return;
    int d = ei[EE + e];
    int p = offs[d] + atomicAdd(&cur[d], 1);
    csr[p] = ei[e];
}

// ---------------- mean aggregation layer0: gather A0 cols 80..159 -> cols 0..79 ----------------
__global__ __launch_bounds__(256) void agg0_kernel(
    unsigned short* __restrict__ A0, const int* __restrict__ csr,
    const int* __restrict__ offs, const int* __restrict__ deg,
    const float* __restrict__ invdeg)
{
    int node = blockIdx.x * 8 + (threadIdx.x >> 5);
    int lane = threadIdx.x & 31;
    if (node >= NP || lane >= 20) return;
    int d = 0, st = 0; float iv = 0.f;
    if (node < NN) { d = deg[node]; st = offs[node]; iv = invdeg[node]; }
    float s0=0.f, s1=0.f, s2=0.f, s3=0.f;
    int e = 0;
    for (; e + 4 <= d; e += 4) {
        int i0 = csr[st + e], i1 = csr[st + e + 1];
        int i2 = csr[st + e + 2], i3 = csr[st + e + 3];
        ushort4 v0 = *(const ushort4*)(A0 + (size_t)i0 * 160 + 80 + lane * 4);
        ushort4 v1 = *(const ushort4*)(A0 + (size_t)i1 * 160 + 80 + lane * 4);
        ushort4 v2 = *(const ushort4*)(A0 + (size_t)i2 * 160 + 80 + lane * 4);
        ushort4 v3 = *(const ushort4*)(A0 + (size_t)i3 * 160 + 80 + lane * 4);
        s0 += (bf2f(v0.x) + bf2f(v1.x)) + (bf2f(v2.x) + bf2f(v3.x));
        s1 += (bf2f(v0.y) + bf2f(v1.y)) + (bf2f(v2.y) + bf2f(v3.y));
        s2 += (bf2f(v0.z) + bf2f(v1.z)) + (bf2f(v2.z) + bf2f(v3.z));
        s3 += (bf2f(v0.w) + bf2f(v1.w)) + (bf2f(v2.w) + bf2f(v3.w));
    }
    for (; e < d; ++e) {
        int i0 = csr[st + e];
        ushort4 v0 = *(const ushort4*)(A0 + (size_t)i0 * 160 + 80 + lane * 4);
        s0 += bf2f(v0.x); s1 += bf2f(v0.y); s2 += bf2f(v0.z); s3 += bf2f(v0.w);
    }
    ushort4 o;
    o.x = f2bf(s0 * iv); o.y = f2bf(s1 * iv); o.z = f2bf(s2 * iv); o.w = f2bf(s3 * iv);
    *(ushort4*)(A0 + (size_t)node * 160 + lane * 4) = o;
}

// ---------------- mean aggregation layer1: gather A1 cols 128..255 -> cols 0..127 ----------------
__device__ __forceinline__ void acc8(float* s, uint4 v) {
    s[0] += __uint_as_float(v.x << 16);
    s[1] += __uint_as_float(v.x & 0xffff0000u);
    s[2] += __uint_as_float(v.y << 16);
    s[3] += __uint_as_float(v.y & 0xffff0000u);
    s[4] += __uint_as_float(v.z << 16);
    s[5] += __uint_as_float(v.z & 0xffff0000u);
    s[6] += __uint_as_float(v.w << 16);
    s[7] += __uint_as_float(v.w & 0xffff0000u);
}

__global__ __launch_bounds__(256) void agg1_kernel(
    unsigned short* __restrict__ A1, const int* __restrict__ csr,
    const int* __restrict__ offs, const int* __restrict__ deg,
    const float* __restrict__ invdeg)
{
    int node = blockIdx.x * 16 + (threadIdx.x >> 4);
    int lane = threadIdx.x & 15;
    if (node >= NP) return;
    int d = 0, st = 0; float iv = 0.f;
    if (node < NN) { d = deg[node]; st = offs[node]; iv = invdeg[node]; }
    float s[8];
    #pragma unroll
    for (int i = 0; i < 8; ++i) s[i] = 0.f;
    int e = 0;
    for (; e + 4 <= d; e += 4) {
        int i0 = csr[st + e], i1 = csr[st + e + 1];
        int i2 = csr[st + e + 2], i3 = csr[st + e + 3];
        uint4 v0 = *(const uint4*)(A1 + (size_t)i0 * 256 + 128 + lane * 8);
        uint4 v1 = *(const uint4*)(A1 + (size_t)i1 * 256 + 128 + lane * 8);
        uint4 v2 = *(const uint4*)(A1 + (size_t)i2 * 256 + 128 + lane * 8);
        uint4 v3 = *(const uint4*)(A1 + (size_t)i3 * 256 + 128 + lane * 8);
        acc8(s, v0); acc8(s, v1); acc8(s, v2); acc8(s, v3);
    }
    for (; e < d; ++e) {
        int i0 = csr[st + e];
        uint4 v0 = *(const uint4*)(A1 + (size_t)i0 * 256 + 128 + lane * 8);
        acc8(s, v0);
    }
    uint4 o;
    o.x = pack2(s[0] * iv, s[1] * iv);
    o.y = pack2(s[2] * iv, s[3] * iv);
    o.z = pack2(s[4] * iv, s[5] * iv);
    o.w = pack2(s[6] * iv, s[7] * iv);
    *(uint4*)(A1 + (size_t)node * 256 + lane * 8) = o;
}

// ---------------- MFMA GEMM + LayerNorm + ReLU, register-resident B ----------------
// C[node][j] = relu(LN(A[node][:] @ Wt[j][:] + bias[j]))
// block = 256 thr = 4 waves; 64 nodes x 128 cols per block.
// Wave w covers cols [32w, 32w+32) (nt = 2w, 2w+1) for ALL 64 nodes;
// its B fragments (2 x K/32) live in registers for the whole kernel.
// A-frag:  node = mtile*16 + (lane&15), k = (lane>>4)*8 + j   [m120]
// C/D:     col-lane = lane&15, row = (lane>>4)*4 + reg        [m89]
// LN spans 4 waves -> 16-lane shfl partials -> LDS -> finalize.
template<int K, bool OUTF>
__global__ __launch_bounds__(256, 2) void gemm_regB_ln_kernel(
    const unsigned short* __restrict__ A,
    const unsigned short* __restrict__ Wt,
    const float* __restrict__ bias, const float* __restrict__ gamma,
    const float* __restrict__ beta,
    unsigned short* __restrict__ outB, float* __restrict__ outF)
{
    constexpr int KT  = K / 32;    // k-tiles of 32
    constexpr int AS  = K + 8;     // LDS row stride (shorts): +8 -> 2-way bank alias (free)
    constexpr int CPR = K / 8;     // 16B chunks per row
    __shared__ __align__(16) unsigned short Asm[64 * AS];
    __shared__ __align__(16) float sP[64 * 4];
    __shared__ __align__(16) float qP[64 * 4];

    const int tid = threadIdx.x;
    const int n0 = blockIdx.x * 64;

    // stage A tile (coalesced 16B chunks)
    for (int i = tid; i < 64 * CPR; i += 256) {
        int node = i / CPR, c = i - node * CPR;
        uint4 v = *(const uint4*)(A + (size_t)(n0 + node) * K + c * 8);
        *(uint4*)(Asm + node * AS + c * 8) = v;
    }

    const int l = tid & 63, w = tid >> 6;
    const int g = l >> 4, c0 = l & 15;

    // B fragments: loaded once, register-resident (L2-hot: same 64KB for all blocks)
    bf16x8 bfr[KT][2];
    #pragma unroll
    for (int j = 0; j < 2; ++j) {
        const unsigned short* bp = Wt + (size_t)((2 * w + j) * 16 + c0) * K + g * 8;
        #pragma unroll
        for (int kt = 0; kt < KT; ++kt)
            bfr[kt][j] = *(const bf16x8*)(bp + kt * 32);
    }

    float bia[2], gam[2], bet[2];
    #pragma unroll
    for (int j = 0; j < 2; ++j) {
        int col = (2 * w + j) * 16 + c0;
        bia[j] = bias[col]; gam[j] = gamma[col]; bet[j] = beta[col];
    }

    __syncthreads();

    f32x4 acc[4][2];
    #pragma unroll
    for (int m = 0; m < 4; ++m) {
        acc[m][0] = (f32x4){0.f, 0.f, 0.f, 0.f};
        acc[m][1] = (f32x4){0.f, 0.f, 0.f, 0.f};
    }

    #pragma unroll
    for (int m = 0; m < 4; ++m) {
        const unsigned short* ar = Asm + (m * 16 + c0) * AS + g * 8;
        #pragma unroll
        for (int kt = 0; kt < KT; ++kt) {
            bf16x8 a = *(const bf16x8*)(ar + kt * 32);
            acc[m][0] = __builtin_amdgcn_mfma_f32_16x16x32_bf16(a, bfr[kt][0], acc[m][0], 0, 0, 0);
            acc[m][1] = __builtin_amdgcn_mfma_f32_16x16x32_bf16(a, bfr[kt][1], acc[m][1], 0, 0, 0);
        }
    }

    // phase 1: per-wave LN partials over this wave's 32 cols
    #pragma unroll
    for (int m = 0; m < 4; ++m) {
        #pragma unroll
        for (int r = 0; r < 4; ++r) {
            float h0 = acc[m][0][r] + bia[0];
            float h1 = acc[m][1][r] + bia[1];
            float s = h0 + h1, q = h0 * h0 + h1 * h1;
            #pragma unroll
            for (int mm = 1; mm < 16; mm <<= 1) {
                s += __shfl_xor(s, mm, 64);
                q += __shfl_xor(q, mm, 64);
            }
            if (c0 == 0) {
                int node = m * 16 + g * 4 + r;
                sP[node * 4 + w] = s;
                qP[node * 4 + w] = q;
            }
        }
    }
    __syncthreads();

    // phase 2: finalize LN + ReLU + store
    #pragma unroll
    for (int m = 0; m < 4; ++m) {
        #pragma unroll
        for (int r = 0; r < 4; ++r) {
            int node = m * 16 + g * 4 + r;
            float4 sv = *(const float4*)&sP[node * 4];   // broadcast read
            float4 qv = *(const float4*)&qP[node * 4];
            float s = (sv.x + sv.y) + (sv.z + sv.w);
            float q = (qv.x + qv.y) + (qv.z + qv.w);
            float mu   = s * (1.f / 128.f);
            float var  = q * (1.f / 128.f) - mu * mu;
            float rinv = rsqrtf(var + LN_EPS);
            float h0 = acc[m][0][r] + bia[0];
            float h1 = acc[m][1][r] + bia[1];
            float v0 = fmaxf(0.f, (h0 - mu) * rinv * gam[0] + bet[0]);
            float v1 = fmaxf(0.f, (h1 - mu) * rinv * gam[1] + bet[1]);
            size_t gn = (size_t)(n0 + node);
            if (OUTF) {
                outF[gn * 128 + (2 * w) * 16 + c0]     = v0;
                outF[gn * 128 + (2 * w + 1) * 16 + c0] = v1;
            } else {
                outB[gn * 256 + 128 + (2 * w) * 16 + c0]     = f2bf(v0);
                outB[gn * 256 + 128 + (2 * w + 1) * 16 + c0] = f2bf(v1);
            }
        }
    }
}

// ---------------- graph pooling (batch is sorted) ----------------
__global__ __launch_bounds__(128) void pool_kernel(
    const float* __restrict__ H, const int* __restrict__ batch,
    float* __restrict__ psum, int* __restrict__ pmax, int* __restrict__ cnt)
{
    int j = threadIdx.x;                 // 128 features
    int nbeg = blockIdx.x * 128;
    int nend = nbeg + 128; if (nend > NN) nend = NN;
    if (nbeg >= NN) return;
    int curg = batch[nbeg];
    float s = 0.0f, m = 0.0f;
    int c = 0;
    for (int n = nbeg; n < nend; ++n) {
        int g = batch[n];
        if (g != curg) {
            atomicAdd(&psum[curg * 128 + j], s);
            atomicMax(&pmax[curg * 128 + j], __float_as_int(m));
            if (j == 0) atomicAdd(&cnt[curg], c);
            s = 0.0f; m = 0.0f; c = 0; curg = g;
        }
        float v = H[(size_t)n * 128 + j];
        s += v; m = fmaxf(m, v); ++c;
    }
    atomicAdd(&psum[curg * 128 + j], s);
    atomicMax(&pmax[curg * 128 + j], __float_as_int(m));
    if (j == 0) atomicAdd(&cnt[curg], c);
}

// ---------------- final MLP (one block per graph) ----------------
__global__ __launch_bounds__(64) void mlp_kernel(
    const float* __restrict__ psum, const int* __restrict__ pmax,
    const int* __restrict__ cnt,
    const float* __restrict__ Wf0, const float* __restrict__ bf0,
    const float* __restrict__ Wf1, const float* __restrict__ bf1,
    const float* __restrict__ Wf2, const float* __restrict__ bf2,
    float* __restrict__ out)
{
    __shared__ float z[256];
    __shared__ float t1[50];
    __shared__ float t2[50];
    int g = blockIdx.x, t = threadIdx.x;
    int c = cnt[g];
    float ic = 1.0f / (float)(c > 1 ? c : 1);
    for (int j = t; j < 128; j += 64) {
        z[j]       = psum[g * 128 + j] * ic;
        z[128 + j] = __int_as_float(pmax[g * 128 + j]);
    }
    __syncthreads();
    if (t < 50) {
        float a = bf0[t];
        for (int k = 0; k < 256; ++k) a = fmaf(z[k], Wf0[k * 50 + t], a);
        t1[t] = fmaxf(a, 0.0f);
    }
    __syncthreads();
    if (t < 50) {
        float a = bf1[t];
        for (int k = 0; k < 50; ++k) a = fmaf(t1[k], Wf1[k * 50 + t], a);
        t2[t] = fmaxf(a, 0.0f);
    }
    __syncthreads();
    if (t < 10) {
        float a = bf2[t];
        for (int k = 0; k < 50; ++k) a = fmaf(t2[k], Wf2[k * 10 + t], a);
        out[g * 10 + t] = fmaxf(a, 0.0f);
    }
}

// ---------------- launcher ----------------
extern "C" void kernel_launch(void* const* d_in, const int* in_sizes, int n_in,
                              void* d_out, int out_size, void* d_ws, size_t ws_size,
                              hipStream_t stream)
{
    const float* x     = (const float*)d_in[0];
    const float* xdims = (const float*)d_in[1];
    const int*   stt   = (const int*)d_in[2];
    const int*   ei    = (const int*)d_in[3];
    const int*   batch = (const int*)d_in[4];
    const float* emb   = (const float*)d_in[5];
    const float* Wl0   = (const float*)d_in[6];
    const float* bl0   = (const float*)d_in[7];
    const float* Wr0   = (const float*)d_in[8];
    const float* g0    = (const float*)d_in[9];
    const float* bn0   = (const float*)d_in[10];
    const float* Wl1   = (const float*)d_in[11];
    const float* bl1   = (const float*)d_in[12];
    const float* Wr1   = (const float*)d_in[13];
    const float* g1    = (const float*)d_in[14];
    const float* bn1   = (const float*)d_in[15];
    const float* Wf0   = (const float*)d_in[16];
    const float* bf0   = (const float*)d_in[17];
    const float* Wf1   = (const float*)d_in[18];
    const float* bf1   = (const float*)d_in[19];
    const float* Wf2   = (const float*)d_in[20];
    const float* bf2   = (const float*)d_in[21];

    char* w = (char*)d_ws;
    // region R1: A0 (bf16 [NP][160] = 32MB) early, H2 (f32 [NP][128] = 51.25MB) late.
    // A0 is dead once gemm0 has run; H2 is written by gemm1 (after gemm0). Safe alias.
    unsigned short* A0 = (unsigned short*)w;
    float*          H2 = (float*)w;          w += (size_t)NP * 128 * 4;
    unsigned short* A1 = (unsigned short*)w; w += (size_t)NP * 256 * 2;
    unsigned short* Wt0 = (unsigned short*)w; w += (size_t)128 * 160 * 2;
    unsigned short* Wt1 = (unsigned short*)w; w += (size_t)128 * 256 * 2;
    int*   csr  = (int*)w;   w += (size_t)EE * 4;
    int*   offs = (int*)w;   w += (size_t)NN * 4;
    float* invdeg = (float*)w; w += (size_t)NN * 4;
    int*   bsum = (int*)w;   w += 1024;
    // zeroed region (one memset):
    char* zbeg = w;
    int*   deg  = (int*)w;   w += (size_t)NP * 4;
    int*   cur  = (int*)w;   w += (size_t)NN * 4;
    int*   cnt  = (int*)w;   w += (size_t)GG * 4;
    float* psum = (float*)w; w += (size_t)GG * 128 * 4;
    int*   pmax = (int*)w;   w += (size_t)GG * 128 * 4;
    size_t zsz = (size_t)(w - zbeg);

    hipMemsetAsync(zbeg, 0, zsz, stream);

    wtprep_kernel<<<(128 * 160 + 128 * 256 + 255) / 256, 256, 0, stream>>>(
        Wl0, Wr0, Wl1, Wr1, Wt0, Wt1);
    assemble_kernel<<<(NP * 80) / 256, 256, 0, stream>>>(x, xdims, stt, emb, A0);

    count_deg_kernel<<<(EE + 255) / 256, 256, 0, stream>>>(ei, deg);
    int nb = (NN + 2047) / 2048;
    scan1_kernel<<<nb, 256, 0, stream>>>(deg, offs, bsum);
    scan2_kernel<<<1, 64, 0, stream>>>(bsum, nb);
    scan3_kernel<<<(NN + 255) / 256, 256, 0, stream>>>(offs, bsum, deg, invdeg);
    fill_csr_kernel<<<(EE + 255) / 256, 256, 0, stream>>>(ei, cur, offs, csr);

    // layer 0: agg h0 -> A0 cols 0..79; gemm -> h1 (bf16) into A1 cols 128..255
    agg0_kernel<<<NP / 8, 256, 0, stream>>>(A0, csr, offs, deg, invdeg);
    gemm_regB_ln_kernel<160, false><<<NP / 64, 256, 0, stream>>>(
        A0, Wt0, bl0, g0, bn0, A1, nullptr);
    // layer 1: agg h1 -> A1 cols 0..127; gemm -> h2 (f32) into H2
    agg1_kernel<<<NP / 16, 256, 0, stream>>>(A1, csr, offs, deg, invdeg);
    gemm_regB_ln_kernel<256, true><<<NP / 64, 256, 0, stream>>>(
        A1, Wt1, bl1, g1, bn1, nullptr, H2);

    pool_kernel<<<(NN + 127) / 128, 128, 0, stream>>>(H2, batch, psum, pmax, cnt);
    mlp_kernel<<<GG, 64, 0, stream>>>(psum, pmax, cnt, Wf0, bf0, Wf1, bf1, Wf2, bf2,
                                      (float*)d_out);
}

// Round 4
// 353.676 us; speedup vs baseline: 2.2632x; 1.0044x over previous
//
#include <hip/hip_runtime.h>

#define NN 100000
#define NP 100096          // padded to multiple of 64
#define EE 600000
#define GG 512
#define LN_EPS 1e-5f

typedef __attribute__((ext_vector_type(8))) __bf16 bf16x8;
typedef __attribute__((ext_vector_type(4))) float f32x4;

__device__ __forceinline__ float bf2f(unsigned short u) {
    return __uint_as_float(((unsigned int)u) << 16);
}
__device__ __forceinline__ unsigned short f2bf(float f) {
    unsigned int u = __float_as_uint(f);
    u = (u + 0x7fffu + ((u >> 16) & 1u)) >> 16;
    return (unsigned short)u;
}
__device__ __forceinline__ unsigned int pack2(float a, float b) {
    return (unsigned int)f2bf(a) | ((unsigned int)f2bf(b) << 16);
}
__device__ __forceinline__ void acc8(float* s, uint4 v) {
    s[0] += __uint_as_float(v.x << 16);
    s[1] += __uint_as_float(v.x & 0xffff0000u);
    s[2] += __uint_as_float(v.y << 16);
    s[3] += __uint_as_float(v.y & 0xffff0000u);
    s[4] += __uint_as_float(v.z << 16);
    s[5] += __uint_as_float(v.z & 0xffff0000u);
    s[6] += __uint_as_float(v.w << 16);
    s[7] += __uint_as_float(v.w & 0xffff0000u);
}

// ---------------- assemble H0 (bf16 [NP][80]) = [x | xdims | emb[stt] | 0pad] ----------------
__global__ __launch_bounds__(256) void assemble_kernel(
    const float* __restrict__ x, const float* __restrict__ xdims,
    const int* __restrict__ stt, const float* __restrict__ emb,
    unsigned short* __restrict__ H0)
{
    int idx = blockIdx.x * 256 + threadIdx.x;   // over NP*80
    int n = idx / 80, c = idx - n * 80;
    if (n >= NP) return;
    float v = 0.f;
    if (n < NN) {
        if (c < 60)      v = x[n * 60 + c];
        else if (c < 62) v = xdims[n * 2 + (c - 60)];
        else if (c < 74) v = emb[stt[n] * 12 + (c - 62)];
    }
    H0[(size_t)n * 80 + c] = f2bf(v);
}

// ---------------- weight transpose+pad to bf16 Wt[n][k] (both layers) ----------------
__global__ __launch_bounds__(256) void wtprep_kernel(
    const float* __restrict__ Wl0, const float* __restrict__ Wr0,
    const float* __restrict__ Wl1, const float* __restrict__ Wr1,
    unsigned short* __restrict__ Wt0, unsigned short* __restrict__ Wt1)
{
    int idx = blockIdx.x * 256 + threadIdx.x;
    if (idx < 128 * 160) {
        int n = idx / 160, k = idx - n * 160;
        float v = 0.f;
        if (k < 74)                  v = Wl0[k * 128 + n];
        else if (k >= 80 && k < 154) v = Wr0[(k - 80) * 128 + n];
        Wt0[(size_t)n * 160 + k] = f2bf(v);
    } else if (idx < 128 * 160 + 128 * 256) {
        int j = idx - 128 * 160;
        int n = j >> 8, k = j & 255;
        float v = (k < 128) ? Wl1[k * 128 + n] : Wr1[(k - 128) * 128 + n];
        Wt1[(size_t)n * 256 + k] = f2bf(v);
    }
}

// ---------------- degree count ----------------
__global__ __launch_bounds__(256) void count_deg_kernel(
    const int* __restrict__ ei, int* __restrict__ deg)
{
    int e = blockIdx.x * 256 + threadIdx.x;
    if (e >= EE) return;
    atomicAdd(&deg[ei[EE + e]], 1);
}

// ---------------- exclusive scan of deg -> offs ----------------
__global__ __launch_bounds__(256) void scan1_kernel(
    const int* __restrict__ deg, int* __restrict__ offs, int* __restrict__ bsum)
{
    __shared__ int ts[256];
    int t = threadIdx.x;
    int base = blockIdx.x * 2048 + t * 8;
    int d[8];
    if (base + 8 <= NN) {
        int4 a = *(const int4*)&deg[base];
        int4 b = *(const int4*)&deg[base + 4];
        d[0]=a.x; d[1]=a.y; d[2]=a.z; d[3]=a.w;
        d[4]=b.x; d[5]=b.y; d[6]=b.z; d[7]=b.w;
    } else {
        #pragma unroll
        for (int i = 0; i < 8; ++i) d[i] = (base + i < NN) ? deg[base + i] : 0;
    }
    int e[8]; int run = 0;
    #pragma unroll
    for (int i = 0; i < 8; ++i) { e[i] = run; run += d[i]; }
    ts[t] = run;
    int tot = run;
    __syncthreads();
    for (int off = 1; off < 256; off <<= 1) {
        int u = (t >= off) ? ts[t - off] : 0;
        __syncthreads();
        ts[t] += u;
        __syncthreads();
    }
    int pre = ts[t] - tot;
    #pragma unroll
    for (int i = 0; i < 8; ++i) if (base + i < NN) offs[base + i] = e[i] + pre;
    if (t == 255) bsum[blockIdx.x] = ts[255];
}

__global__ void scan2_kernel(int* __restrict__ bsum, int nb)
{
    int t = threadIdx.x;   // 64 threads, one wave
    int v = (t < nb) ? bsum[t] : 0;
    int inc = v;
    for (int off = 1; off < 64; off <<= 1) {
        int u = __shfl_up(inc, off, 64);
        if (t >= off) inc += u;
    }
    if (t < nb) bsum[t] = inc - v;   // exclusive
}

__global__ __launch_bounds__(256) void scan3_kernel(
    int* __restrict__ offs, const int* __restrict__ bsum,
    const int* __restrict__ deg, float* __restrict__ invdeg)
{
    int i = blockIdx.x * 256 + threadIdx.x;
    if (i >= NN) return;
    offs[i] += bsum[i / 2048];
    int d = deg[i];
    invdeg[i] = 1.0f / (float)(d > 1 ? d : 1);
}

// ---------------- CSR fill ----------------
__global__ __launch_bounds__(256) void fill_csr_kernel(
    const int* __restrict__ ei, int* __restrict__ cur,
    const int* __restrict__ offs, int* __restrict__ csr)
{
    int e = blockIdx.x * 256 + threadIdx.x;
    if (e >= EE) return;
    int d = ei[EE + e];
    int p = offs[d] + atomicAdd(&cur[d], 1);
    csr[p] = ei[e];
}

// ---------------- layer0: fused gather + MFMA GEMM + LN + ReLU -> H1 ----------------
// A row (K=160): cols 0..79 = mean_j H0[j], cols 80..159 = H0[node]
__global__ __launch_bounds__(256, 2) void gemm0_fused_kernel(
    const unsigned short* __restrict__ H0,
    const int* __restrict__ csr, const int* __restrict__ offs,
    const int* __restrict__ deg, const float* __restrict__ invdeg,
    const unsigned short* __restrict__ Wt,
    const float* __restrict__ bias, const float* __restrict__ gamma,
    const float* __restrict__ beta,
    unsigned short* __restrict__ H1)
{
    constexpr int K = 160, KT = K / 32, AS = K + 8;
    __shared__ __align__(16) unsigned short Asm[64 * AS];
    __shared__ __align__(16) float sP[64 * 4];
    __shared__ __align__(16) float qP[64 * 4];

    const int tid = threadIdx.x;
    const int n0 = blockIdx.x * 64;

    // B fragments: register-resident for whole kernel
    const int l = tid & 63, w = tid >> 6;
    const int g = l >> 4, c0 = l & 15;
    bf16x8 bfr[KT][2];
    #pragma unroll
    for (int j = 0; j < 2; ++j) {
        const unsigned short* bp = Wt + (size_t)((2 * w + j) * 16 + c0) * K + g * 8;
        #pragma unroll
        for (int kt = 0; kt < KT; ++kt)
            bfr[kt][j] = *(const bf16x8*)(bp + kt * 32);
    }
    float bia[2], gam[2], bet[2];
    #pragma unroll
    for (int j = 0; j < 2; ++j) {
        int col = (2 * w + j) * 16 + c0;
        bia[j] = bias[col]; gam[j] = gamma[col]; bet[j] = beta[col];
    }

    // stage root features: cols 80..159  (10 x uint4 per node)
    for (int i = tid; i < 64 * 10; i += 256) {
        int node = i / 10, c = i - node * 10;
        uint4 v = *(const uint4*)(H0 + (size_t)(n0 + node) * 80 + c * 8);
        *(uint4*)(Asm + node * AS + 80 + c * 8) = v;
    }
    // gather neighbor mean: cols 0..79; 16 groups x 16 lanes (10 active), 4 passes
    {
        int grp = tid >> 4, ln = tid & 15;
        #pragma unroll
        for (int pass = 0; pass < 4; ++pass) {
            int node = pass * 16 + grp;
            int gn = n0 + node;
            int d = 0, st = 0; float iv = 0.f;
            if (gn < NN) { d = deg[gn]; st = offs[gn]; iv = invdeg[gn]; }
            if (ln < 10) {
                float s[8];
                #pragma unroll
                for (int i = 0; i < 8; ++i) s[i] = 0.f;
                int e = 0;
                for (; e + 4 <= d; e += 4) {
                    int i0 = csr[st + e],     i1 = csr[st + e + 1];
                    int i2 = csr[st + e + 2], i3 = csr[st + e + 3];
                    uint4 v0 = *(const uint4*)(H0 + (size_t)i0 * 80 + ln * 8);
                    uint4 v1 = *(const uint4*)(H0 + (size_t)i1 * 80 + ln * 8);
                    uint4 v2 = *(const uint4*)(H0 + (size_t)i2 * 80 + ln * 8);
                    uint4 v3 = *(const uint4*)(H0 + (size_t)i3 * 80 + ln * 8);
                    acc8(s, v0); acc8(s, v1); acc8(s, v2); acc8(s, v3);
                }
                for (; e < d; ++e) {
                    int i0 = csr[st + e];
                    uint4 v0 = *(const uint4*)(H0 + (size_t)i0 * 80 + ln * 8);
                    acc8(s, v0);
                }
                uint4 o;
                o.x = pack2(s[0] * iv, s[1] * iv);
                o.y = pack2(s[2] * iv, s[3] * iv);
                o.z = pack2(s[4] * iv, s[5] * iv);
                o.w = pack2(s[6] * iv, s[7] * iv);
                *(uint4*)(Asm + node * AS + ln * 8) = o;
            }
        }
    }
    __syncthreads();

    f32x4 acc[4][2];
    #pragma unroll
    for (int m = 0; m < 4; ++m) {
        acc[m][0] = (f32x4){0.f, 0.f, 0.f, 0.f};
        acc[m][1] = (f32x4){0.f, 0.f, 0.f, 0.f};
    }
    #pragma unroll
    for (int m = 0; m < 4; ++m) {
        const unsigned short* ar = Asm + (m * 16 + c0) * AS + g * 8;
        #pragma unroll
        for (int kt = 0; kt < KT; ++kt) {
            bf16x8 a = *(const bf16x8*)(ar + kt * 32);
            acc[m][0] = __builtin_amdgcn_mfma_f32_16x16x32_bf16(a, bfr[kt][0], acc[m][0], 0, 0, 0);
            acc[m][1] = __builtin_amdgcn_mfma_f32_16x16x32_bf16(a, bfr[kt][1], acc[m][1], 0, 0, 0);
        }
    }

    // LN phase 1: per-wave partials over this wave's 32 cols
    #pragma unroll
    for (int m = 0; m < 4; ++m) {
        #pragma unroll
        for (int r = 0; r < 4; ++r) {
            float h0v = acc[m][0][r] + bia[0];
            float h1v = acc[m][1][r] + bia[1];
            float s = h0v + h1v, q = h0v * h0v + h1v * h1v;
            #pragma unroll
            for (int mm = 1; mm < 16; mm <<= 1) {
                s += __shfl_xor(s, mm, 64);
                q += __shfl_xor(q, mm, 64);
            }
            if (c0 == 0) {
                int node = m * 16 + g * 4 + r;
                sP[node * 4 + w] = s;
                qP[node * 4 + w] = q;
            }
        }
    }
    __syncthreads();

    // LN phase 2 + ReLU + store bf16
    #pragma unroll
    for (int m = 0; m < 4; ++m) {
        #pragma unroll
        for (int r = 0; r < 4; ++r) {
            int node = m * 16 + g * 4 + r;
            float4 sv = *(const float4*)&sP[node * 4];
            float4 qv = *(const float4*)&qP[node * 4];
            float s = (sv.x + sv.y) + (sv.z + sv.w);
            float q = (qv.x + qv.y) + (qv.z + qv.w);
            float mu   = s * (1.f / 128.f);
            float var  = q * (1.f / 128.f) - mu * mu;
            float rinv = rsqrtf(var + LN_EPS);
            float h0v = acc[m][0][r] + bia[0];
            float h1v = acc[m][1][r] + bia[1];
            float v0 = fmaxf(0.f, (h0v - mu) * rinv * gam[0] + bet[0]);
            float v1 = fmaxf(0.f, (h1v - mu) * rinv * gam[1] + bet[1]);
            size_t gn = (size_t)(n0 + node);
            H1[gn * 128 + (2 * w) * 16 + c0]     = f2bf(v0);
            H1[gn * 128 + (2 * w + 1) * 16 + c0] = f2bf(v1);
        }
    }
}

// ---------------- layer1: fused gather + MFMA GEMM + LN + ReLU + pooling ----------------
// A row (K=256): cols 0..127 = mean_j H1[j], cols 128..255 = H1[node]
__global__ __launch_bounds__(256, 2) void gemm1_fused_kernel(
    const unsigned short* __restrict__ H1,
    const int* __restrict__ csr, const int* __restrict__ offs,
    const int* __restrict__ deg, const float* __restrict__ invdeg,
    const unsigned short* __restrict__ Wt,
    const float* __restrict__ bias, const float* __restrict__ gamma,
    const float* __restrict__ beta,
    const int* __restrict__ batch,
    float* __restrict__ psum, int* __restrict__ pmax)
{
    constexpr int K = 256, KT = K / 32, AS = K + 8;
    // Asm (64*AS shorts = 33792B) aliased with Hs (64*128 f32 = 32768B) after MFMA
    __shared__ __align__(16) char smem[64 * AS * 2];
    unsigned short* Asm = (unsigned short*)smem;
    float* Hs = (float*)smem;
    __shared__ __align__(16) float sP[64 * 4];
    __shared__ __align__(16) float qP[64 * 4];
    __shared__ int bS[64];

    const int tid = threadIdx.x;
    const int n0 = blockIdx.x * 64;

    const int l = tid & 63, w = tid >> 6;
    const int g = l >> 4, c0 = l & 15;
    bf16x8 bfr[KT][2];
    #pragma unroll
    for (int j = 0; j < 2; ++j) {
        const unsigned short* bp = Wt + (size_t)((2 * w + j) * 16 + c0) * K + g * 8;
        #pragma unroll
        for (int kt = 0; kt < KT; ++kt)
            bfr[kt][j] = *(const bf16x8*)(bp + kt * 32);
    }
    float bia[2], gam[2], bet[2];
    #pragma unroll
    for (int j = 0; j < 2; ++j) {
        int col = (2 * w + j) * 16 + c0;
        bia[j] = bias[col]; gam[j] = gamma[col]; bet[j] = beta[col];
    }

    if (tid < 64) {
        int gn = n0 + tid;
        bS[tid] = (gn < NN) ? batch[gn] : -1;
    }
    // stage root features: cols 128..255  (16 x uint4 per node)
    for (int i = tid; i < 64 * 16; i += 256) {
        int node = i >> 4, c = i & 15;
        uint4 v = *(const uint4*)(H1 + (size_t)(n0 + node) * 128 + c * 8);
        *(uint4*)(Asm + node * AS + 128 + c * 8) = v;
    }
    // gather neighbor mean: cols 0..127; 16 groups x 16 lanes, 4 passes
    {
        int grp = tid >> 4, ln = tid & 15;
        #pragma unroll
        for (int pass = 0; pass < 4; ++pass) {
            int node = pass * 16 + grp;
            int gn = n0 + node;
            int d = 0, st = 0; float iv = 0.f;
            if (gn < NN) { d = deg[gn]; st = offs[gn]; iv = invdeg[gn]; }
            float s[8];
            #pragma unroll
            for (int i = 0; i < 8; ++i) s[i] = 0.f;
            int e = 0;
            for (; e + 4 <= d; e += 4) {
                int i0 = csr[st + e],     i1 = csr[st + e + 1];
                int i2 = csr[st + e + 2], i3 = csr[st + e + 3];
                uint4 v0 = *(const uint4*)(H1 + (size_t)i0 * 128 + ln * 8);
                uint4 v1 = *(const uint4*)(H1 + (size_t)i1 * 128 + ln * 8);
                uint4 v2 = *(const uint4*)(H1 + (size_t)i2 * 128 + ln * 8);
                uint4 v3 = *(const uint4*)(H1 + (size_t)i3 * 128 + ln * 8);
                acc8(s, v0); acc8(s, v1); acc8(s, v2); acc8(s, v3);
            }
            for (; e < d; ++e) {
                int i0 = csr[st + e];
                uint4 v0 = *(const uint4*)(H1 + (size_t)i0 * 128 + ln * 8);
                acc8(s, v0);
            }
            uint4 o;
            o.x = pack2(s[0] * iv, s[1] * iv);
            o.y = pack2(s[2] * iv, s[3] * iv);
            o.z = pack2(s[4] * iv, s[5] * iv);
            o.w = pack2(s[6] * iv, s[7] * iv);
            *(uint4*)(Asm + node * AS + ln * 8) = o;
        }
    }
    __syncthreads();

    f32x4 acc[4][2];
    #pragma unroll
    for (int m = 0; m < 4; ++m) {
        acc[m][0] = (f32x4){0.f, 0.f, 0.f, 0.f};
        acc[m][1] = (f32x4){0.f, 0.f, 0.f, 0.f};
    }
    #pragma unroll
    for (int m = 0; m < 4; ++m) {
        const unsigned short* ar = Asm + (m * 16 + c0) * AS + g * 8;
        #pragma unroll
        for (int kt = 0; kt < KT; ++kt) {
            bf16x8 a = *(const bf16x8*)(ar + kt * 32);
            acc[m][0] = __builtin_amdgcn_mfma_f32_16x16x32_bf16(a, bfr[kt][0], acc[m][0], 0, 0, 0);
            acc[m][1] = __builtin_amdgcn_mfma_f32_16x16x32_bf16(a, bfr[kt][1], acc[m][1], 0, 0, 0);
        }
    }

    // LN phase 1
    #pragma unroll
    for (int m = 0; m < 4; ++m) {
        #pragma unroll
        for (int r = 0; r < 4; ++r) {
            float h0v = acc[m][0][r] + bia[0];
            float h1v = acc[m][1][r] + bia[1];
            float s = h0v + h1v, q = h0v * h0v + h1v * h1v;
            #pragma unroll
            for (int mm = 1; mm < 16; mm <<= 1) {
                s += __shfl_xor(s, mm, 64);
                q += __shfl_xor(q, mm, 64);
            }
            if (c0 == 0) {
                int node = m * 16 + g * 4 + r;
                sP[node * 4 + w] = s;
                qP[node * 4 + w] = q;
            }
        }
    }
    __syncthreads();   // all waves done with MFMA (Asm reads) + phase1

    // LN phase 2 + ReLU -> Hs tile (overwrites Asm region; safe after sync)
    #pragma unroll
    for (int m = 0; m < 4; ++m) {
        #pragma unroll
        for (int r = 0; r < 4; ++r) {
            int node = m * 16 + g * 4 + r;
            float4 sv = *(const float4*)&sP[node * 4];
            float4 qv = *(const float4*)&qP[node * 4];
            float s = (sv.x + sv.y) + (sv.z + sv.w);
            float q = (qv.x + qv.y) + (qv.z + qv.w);
            float mu   = s * (1.f / 128.f);
            float var  = q * (1.f / 128.f) - mu * mu;
            float rinv = rsqrtf(var + LN_EPS);
            float h0v = acc[m][0][r] + bia[0];
            float h1v = acc[m][1][r] + bia[1];
            float v0 = fmaxf(0.f, (h0v - mu) * rinv * gam[0] + bet[0]);
            float v1 = fmaxf(0.f, (h1v - mu) * rinv * gam[1] + bet[1]);
            Hs[node * 128 + (2 * w) * 16 + c0]     = v0;
            Hs[node * 128 + (2 * w + 1) * 16 + c0] = v1;
        }
    }
    __syncthreads();

    // fused pooling: 128 threads, one column each; sorted batch -> few flushes
    if (tid < 128) {
        int j = tid;
        int curg = -1; float s = 0.f, m = 0.f;
        #pragma unroll 4
        for (int n = 0; n < 64; ++n) {
            int gb = bS[n];
            if (gb < 0) break;   // padding tail (sorted: pads only at end)
            if (gb != curg) {
                if (curg >= 0) {
                    atomicAdd(&psum[curg * 128 + j], s);
                    atomicMax(&pmax[curg * 128 + j], __float_as_int(m));
                }
                curg = gb; s = 0.f; m = 0.f;
            }
            float v = Hs[n * 128 + j];
            s += v; m = fmaxf(m, v);
        }
        if (curg >= 0) {
            atomicAdd(&psum[curg * 128 + j], s);
            atomicMax(&pmax[curg * 128 + j], __float_as_int(m));
        }
    }
}

// ---------------- final MLP (one block per graph; cnt via binary search) ----------------
__device__ __forceinline__ int lbound(const int* a, int n, int v) {
    int lo = 0, hi = n;
    while (lo < hi) { int mid = (lo + hi) >> 1; if (a[mid] < v) lo = mid + 1; else hi = mid; }
    return lo;
}

__global__ __launch_bounds__(64) void mlp_kernel(
    const float* __restrict__ psum, const int* __restrict__ pmax,
    const int* __restrict__ batch,
    const float* __restrict__ Wf0, const float* __restrict__ bf0,
    const float* __restrict__ Wf1, const float* __restrict__ bf1,
    const float* __restrict__ Wf2, const float* __restrict__ bf2,
    float* __restrict__ out)
{
    __shared__ float z[256];
    __shared__ float t1[50];
    __shared__ float t2[50];
    __shared__ int cS;
    int g = blockIdx.x, t = threadIdx.x;
    if (t == 0) cS = lbound(batch, NN, g + 1) - lbound(batch, NN, g);
    __syncthreads();
    int c = cS;
    float ic = 1.0f / (float)(c > 1 ? c : 1);
    for (int j = t; j < 128; j += 64) {
        z[j]       = psum[g * 128 + j] * ic;
        z[128 + j] = __int_as_float(pmax[g * 128 + j]);
    }
    __syncthreads();
    if (t < 50) {
        float a = bf0[t];
        for (int k = 0; k < 256; ++k) a = fmaf(z[k], Wf0[k * 50 + t], a);
        t1[t] = fmaxf(a, 0.0f);
    }
    __syncthreads();
    if (t < 50) {
        float a = bf1[t];
        for (int k = 0; k < 50; ++k) a = fmaf(t1[k], Wf1[k * 50 + t], a);
        t2[t] = fmaxf(a, 0.0f);
    }
    __syncthreads();
    if (t < 10) {
        float a = bf2[t];
        for (int k = 0; k < 50; ++k) a = fmaf(t2[k], Wf2[k * 10 + t], a);
        out[g * 10 + t] = fmaxf(a, 0.0f);
    }
}

// ---------------- launcher ----------------
extern "C" void kernel_launch(void* const* d_in, const int* in_sizes, int n_in,
                              void* d_out, int out_size, void* d_ws, size_t ws_size,
                              hipStream_t stream)
{
    const float* x     = (const float*)d_in[0];
    const float* xdims = (const float*)d_in[1];
    const int*   stt   = (const int*)d_in[2];
    const int*   ei    = (const int*)d_in[3];
    const int*   batch = (const int*)d_in[4];
    const float* emb   = (const float*)d_in[5];
    const float* Wl0   = (const float*)d_in[6];
    const float* bl0   = (const float*)d_in[7];
    const float* Wr0   = (const float*)d_in[8];
    const float* g0    = (const float*)d_in[9];
    const float* bn0   = (const float*)d_in[10];
    const float* Wl1   = (const float*)d_in[11];
    const float* bl1   = (const float*)d_in[12];
    const float* Wr1   = (const float*)d_in[13];
    const float* g1    = (const float*)d_in[14];
    const float* bn1   = (const float*)d_in[15];
    const float* Wf0   = (const float*)d_in[16];
    const float* bf0   = (const float*)d_in[17];
    const float* Wf1   = (const float*)d_in[18];
    const float* bf1   = (const float*)d_in[19];
    const float* Wf2   = (const float*)d_in[20];
    const float* bf2   = (const float*)d_in[21];

    char* w = (char*)d_ws;
    unsigned short* H0  = (unsigned short*)w; w += (size_t)NP * 80 * 2;
    unsigned short* H1  = (unsigned short*)w; w += (size_t)NP * 128 * 2;
    unsigned short* Wt0 = (unsigned short*)w; w += (size_t)128 * 160 * 2;
    unsigned short* Wt1 = (unsigned short*)w; w += (size_t)128 * 256 * 2;
    int*   csr    = (int*)w;   w += (size_t)EE * 4;
    int*   offs   = (int*)w;   w += (size_t)NN * 4;
    float* invdeg = (float*)w; w += (size_t)NN * 4;
    int*   bsum   = (int*)w;   w += 1024;
    // zeroed region (one memset):
    char* zbeg = w;
    int*   deg  = (int*)w;   w += (size_t)NP * 4;
    int*   cur  = (int*)w;   w += (size_t)NN * 4;
    float* psum = (float*)w; w += (size_t)GG * 128 * 4;
    int*   pmax = (int*)w;   w += (size_t)GG * 128 * 4;
    size_t zsz = (size_t)(w - zbeg);

    hipMemsetAsync(zbeg, 0, zsz, stream);

    wtprep_kernel<<<(128 * 160 + 128 * 256 + 255) / 256, 256, 0, stream>>>(
        Wl0, Wr0, Wl1, Wr1, Wt0, Wt1);
    assemble_kernel<<<(NP * 80 + 255) / 256, 256, 0, stream>>>(x, xdims, stt, emb, H0);

    count_deg_kernel<<<(EE + 255) / 256, 256, 0, stream>>>(ei, deg);
    int nb = (NN + 2047) / 2048;
    scan1_kernel<<<nb, 256, 0, stream>>>(deg, offs, bsum);
    scan2_kernel<<<1, 64, 0, stream>>>(bsum, nb);
    scan3_kernel<<<(NN + 255) / 256, 256, 0, stream>>>(offs, bsum, deg, invdeg);
    fill_csr_kernel<<<(EE + 255) / 256, 256, 0, stream>>>(ei, cur, offs, csr);

    gemm0_fused_kernel<<<NP / 64, 256, 0, stream>>>(
        H0, csr, offs, deg, invdeg, Wt0, bl0, g0, bn0, H1);
    gemm1_fused_kernel<<<NP / 64, 256, 0, stream>>>(
        H1, csr, offs, deg, invdeg, Wt1, bl1, g1, bn1, batch, psum, pmax);

    mlp_kernel<<<GG, 64, 0, stream>>>(psum, pmax, batch, Wf0, bf0, Wf1, bf1, Wf2, bf2,
                                      (float*)d_out);
}

// Round 5
// 316.158 us; speedup vs baseline: 2.5318x; 1.1187x over previous
//
#include <hip/hip_runtime.h>

#define NN 100000
#define NP 100096          // padded to multiple of 64
#define EE 600000
#define GG 512
#define LN_EPS 1e-5f

typedef __attribute__((ext_vector_type(8))) __bf16 bf16x8;
typedef __attribute__((ext_vector_type(4))) float f32x4;

__device__ __forceinline__ unsigned short f2bf(float f) {
    unsigned int u = __float_as_uint(f);
    u = (u + 0x7fffu + ((u >> 16) & 1u)) >> 16;
    return (unsigned short)u;
}
__device__ __forceinline__ unsigned int pack2(float a, float b) {
    return (unsigned int)f2bf(a) | ((unsigned int)f2bf(b) << 16);
}
__device__ __forceinline__ void acc8(float* s, uint4 v) {
    s[0] += __uint_as_float(v.x << 16);
    s[1] += __uint_as_float(v.x & 0xffff0000u);
    s[2] += __uint_as_float(v.y << 16);
    s[3] += __uint_as_float(v.y & 0xffff0000u);
    s[4] += __uint_as_float(v.z << 16);
    s[5] += __uint_as_float(v.z & 0xffff0000u);
    s[6] += __uint_as_float(v.w << 16);
    s[7] += __uint_as_float(v.w & 0xffff0000u);
}

// ---------------- merged prep: assemble A0 root cols + wtprep both layers + degree count ----
// partition of a flat thread index:
//   [0, NP*10)              assemble: node = i/10, 8-col chunk into A0 cols 80..159
//   [.., +128*160)          Wt0 transpose+pad
//   [.., +128*256)          Wt1 transpose
//   [.., +EE)               degree count (atomics)
#define PREP_A (NP * 10)
#define PREP_W0 (128 * 160)
#define PREP_W1 (128 * 256)
#define PREP_TOT (PREP_A + PREP_W0 + PREP_W1 + EE)

__global__ __launch_bounds__(256) void prep_kernel(
    const float* __restrict__ x, const float* __restrict__ xdims,
    const int* __restrict__ stt, const float* __restrict__ emb,
    const int* __restrict__ ei,
    const float* __restrict__ Wl0, const float* __restrict__ Wr0,
    const float* __restrict__ Wl1, const float* __restrict__ Wr1,
    unsigned short* __restrict__ A0,
    unsigned short* __restrict__ Wt0, unsigned short* __restrict__ Wt1,
    int* __restrict__ deg)
{
    int idx = blockIdx.x * 256 + threadIdx.x;
    if (idx < PREP_A) {
        int node = idx / 10;
        int c8 = (idx - node * 10) * 8;   // feature base 0..72
        unsigned short vals[8];
        if (node < NN) {
            int st = stt[node];
            #pragma unroll
            for (int i = 0; i < 8; ++i) {
                int f = c8 + i;
                float v = 0.f;
                if (f < 60)      v = x[node * 60 + f];
                else if (f < 62) v = xdims[node * 2 + (f - 60)];
                else if (f < 74) v = emb[st * 12 + (f - 62)];
                vals[i] = f2bf(v);
            }
        } else {
            #pragma unroll
            for (int i = 0; i < 8; ++i) vals[i] = 0;
        }
        uint4 o;
        o.x = (unsigned)vals[0] | ((unsigned)vals[1] << 16);
        o.y = (unsigned)vals[2] | ((unsigned)vals[3] << 16);
        o.z = (unsigned)vals[4] | ((unsigned)vals[5] << 16);
        o.w = (unsigned)vals[6] | ((unsigned)vals[7] << 16);
        *(uint4*)(A0 + (size_t)node * 160 + 80 + c8) = o;
    } else if (idx < PREP_A + PREP_W0) {
        int j = idx - PREP_A;
        int n = j / 160, k = j - n * 160;
        float v = 0.f;
        if (k < 74)                  v = Wl0[k * 128 + n];
        else if (k >= 80 && k < 154) v = Wr0[(k - 80) * 128 + n];
        Wt0[(size_t)n * 160 + k] = f2bf(v);
    } else if (idx < PREP_A + PREP_W0 + PREP_W1) {
        int j = idx - PREP_A - PREP_W0;
        int n = j >> 8, k = j & 255;
        float v = (k < 128) ? Wl1[k * 128 + n] : Wr1[(k - 128) * 128 + n];
        Wt1[(size_t)n * 256 + k] = f2bf(v);
    } else if (idx < PREP_TOT) {
        int e = idx - PREP_A - PREP_W0 - PREP_W1;
        atomicAdd(&deg[ei[EE + e]], 1);
    }
}

// ---------------- exclusive scan of deg -> offs (local) + bsum ----------------
__global__ __launch_bounds__(256) void scan1_kernel(
    const int* __restrict__ deg, int* __restrict__ offs, int* __restrict__ bsum)
{
    __shared__ int ts[256];
    int t = threadIdx.x;
    int base = blockIdx.x * 2048 + t * 8;
    int d[8];
    if (base + 8 <= NN) {
        int4 a = *(const int4*)&deg[base];
        int4 b = *(const int4*)&deg[base + 4];
        d[0]=a.x; d[1]=a.y; d[2]=a.z; d[3]=a.w;
        d[4]=b.x; d[5]=b.y; d[6]=b.z; d[7]=b.w;
    } else {
        #pragma unroll
        for (int i = 0; i < 8; ++i) d[i] = (base + i < NN) ? deg[base + i] : 0;
    }
    int e[8]; int run = 0;
    #pragma unroll
    for (int i = 0; i < 8; ++i) { e[i] = run; run += d[i]; }
    ts[t] = run;
    int tot = run;
    __syncthreads();
    for (int off = 1; off < 256; off <<= 1) {
        int u = (t >= off) ? ts[t - off] : 0;
        __syncthreads();
        ts[t] += u;
        __syncthreads();
    }
    int pre = ts[t] - tot;
    #pragma unroll
    for (int i = 0; i < 8; ++i) if (base + i < NN) offs[base + i] = e[i] + pre;
    if (t == 255) bsum[blockIdx.x] = ts[255];
}

__global__ void scan2_kernel(int* __restrict__ bsum, int nb)
{
    int t = threadIdx.x;   // one wave
    int v = (t < nb) ? bsum[t] : 0;
    int inc = v;
    for (int off = 1; off < 64; off <<= 1) {
        int u = __shfl_up(inc, off, 64);
        if (t >= off) inc += u;
    }
    if (t < nb) bsum[t] = inc - v;   // exclusive
}

// ---------------- CSR fill (bsum folded in) ----------------
__global__ __launch_bounds__(256) void fill_csr_kernel(
    const int* __restrict__ ei, int* __restrict__ cur,
    const int* __restrict__ offs, const int* __restrict__ bsum,
    int* __restrict__ csr)
{
    int e = blockIdx.x * 256 + threadIdx.x;
    if (e >= EE) return;
    int d = ei[EE + e];
    int p = offs[d] + bsum[d >> 11] + atomicAdd(&cur[d], 1);
    csr[p] = ei[e];
}

// ---------------- agg0: gather A0 cols 80..159 -> mean into cols 0..79 ----------------
__global__ __launch_bounds__(256) void agg0_kernel(
    unsigned short* __restrict__ A0, const int* __restrict__ csr,
    const int* __restrict__ offs, const int* __restrict__ bsum,
    const int* __restrict__ deg)
{
    int node = blockIdx.x * 16 + (threadIdx.x >> 4);
    int lane = threadIdx.x & 15;
    if (node >= NP || lane >= 10) return;
    int d = 0, st = 0;
    if (node < NN) { d = deg[node]; st = offs[node] + bsum[node >> 11]; }
    float iv = 1.0f / (float)(d > 1 ? d : 1);
    float s[8];
    #pragma unroll
    for (int i = 0; i < 8; ++i) s[i] = 0.f;
    int e = 0;
    for (; e + 4 <= d; e += 4) {
        int i0 = csr[st + e],     i1 = csr[st + e + 1];
        int i2 = csr[st + e + 2], i3 = csr[st + e + 3];
        uint4 v0 = *(const uint4*)(A0 + (size_t)i0 * 160 + 80 + lane * 8);
        uint4 v1 = *(const uint4*)(A0 + (size_t)i1 * 160 + 80 + lane * 8);
        uint4 v2 = *(const uint4*)(A0 + (size_t)i2 * 160 + 80 + lane * 8);
        uint4 v3 = *(const uint4*)(A0 + (size_t)i3 * 160 + 80 + lane * 8);
        acc8(s, v0); acc8(s, v1); acc8(s, v2); acc8(s, v3);
    }
    for (; e < d; ++e) {
        int i0 = csr[st + e];
        uint4 v0 = *(const uint4*)(A0 + (size_t)i0 * 160 + 80 + lane * 8);
        acc8(s, v0);
    }
    uint4 o;
    o.x = pack2(s[0] * iv, s[1] * iv);
    o.y = pack2(s[2] * iv, s[3] * iv);
    o.z = pack2(s[4] * iv, s[5] * iv);
    o.w = pack2(s[6] * iv, s[7] * iv);
    *(uint4*)(A0 + (size_t)node * 160 + lane * 8) = o;
}

// ---------------- agg1: gather A1 cols 128..255 -> mean into cols 0..127 ----------------
__global__ __launch_bounds__(256) void agg1_kernel(
    unsigned short* __restrict__ A1, const int* __restrict__ csr,
    const int* __restrict__ offs, const int* __restrict__ bsum,
    const int* __restrict__ deg)
{
    int node = blockIdx.x * 16 + (threadIdx.x >> 4);
    int lane = threadIdx.x & 15;
    if (node >= NP) return;
    int d = 0, st = 0;
    if (node < NN) { d = deg[node]; st = offs[node] + bsum[node >> 11]; }
    float iv = 1.0f / (float)(d > 1 ? d : 1);
    float s[8];
    #pragma unroll
    for (int i = 0; i < 8; ++i) s[i] = 0.f;
    int e = 0;
    for (; e + 4 <= d; e += 4) {
        int i0 = csr[st + e],     i1 = csr[st + e + 1];
        int i2 = csr[st + e + 2], i3 = csr[st + e + 3];
        uint4 v0 = *(const uint4*)(A1 + (size_t)i0 * 256 + 128 + lane * 8);
        uint4 v1 = *(const uint4*)(A1 + (size_t)i1 * 256 + 128 + lane * 8);
        uint4 v2 = *(const uint4*)(A1 + (size_t)i2 * 256 + 128 + lane * 8);
        uint4 v3 = *(const uint4*)(A1 + (size_t)i3 * 256 + 128 + lane * 8);
        acc8(s, v0); acc8(s, v1); acc8(s, v2); acc8(s, v3);
    }
    for (; e < d; ++e) {
        int i0 = csr[st + e];
        uint4 v0 = *(const uint4*)(A1 + (size_t)i0 * 256 + 128 + lane * 8);
        acc8(s, v0);
    }
    uint4 o;
    o.x = pack2(s[0] * iv, s[1] * iv);
    o.y = pack2(s[2] * iv, s[3] * iv);
    o.z = pack2(s[4] * iv, s[5] * iv);
    o.w = pack2(s[6] * iv, s[7] * iv);
    *(uint4*)(A1 + (size_t)node * 256 + lane * 8) = o;
}

// ---------------- layer0 GEMM (regB) + LN + ReLU -> A1 cols 128..255 ----------------
__global__ __launch_bounds__(256, 2) void gemm0_kernel(
    const unsigned short* __restrict__ A,
    const unsigned short* __restrict__ Wt,
    const float* __restrict__ bias, const float* __restrict__ gamma,
    const float* __restrict__ beta,
    unsigned short* __restrict__ A1)
{
    constexpr int K = 160, KT = K / 32, AS = K + 8, CPR = K / 8;
    __shared__ __align__(16) unsigned short Asm[64 * AS];
    __shared__ __align__(16) float sP[64 * 4];
    __shared__ __align__(16) float qP[64 * 4];

    const int tid = threadIdx.x;
    const int n0 = blockIdx.x * 64;

    for (int i = tid; i < 64 * CPR; i += 256) {
        int node = i / CPR, c = i - node * CPR;
        uint4 v = *(const uint4*)(A + (size_t)(n0 + node) * K + c * 8);
        *(uint4*)(Asm + node * AS + c * 8) = v;
    }

    const int l = tid & 63, w = tid >> 6;
    const int g = l >> 4, c0 = l & 15;
    bf16x8 bfr[KT][2];
    #pragma unroll
    for (int j = 0; j < 2; ++j) {
        const unsigned short* bp = Wt + (size_t)((2 * w + j) * 16 + c0) * K + g * 8;
        #pragma unroll
        for (int kt = 0; kt < KT; ++kt)
            bfr[kt][j] = *(const bf16x8*)(bp + kt * 32);
    }
    float bia[2], gam[2], bet[2];
    #pragma unroll
    for (int j = 0; j < 2; ++j) {
        int col = (2 * w + j) * 16 + c0;
        bia[j] = bias[col]; gam[j] = gamma[col]; bet[j] = beta[col];
    }
    __syncthreads();

    f32x4 acc[4][2];
    #pragma unroll
    for (int m = 0; m < 4; ++m) {
        acc[m][0] = (f32x4){0.f, 0.f, 0.f, 0.f};
        acc[m][1] = (f32x4){0.f, 0.f, 0.f, 0.f};
    }
    #pragma unroll
    for (int m = 0; m < 4; ++m) {
        const unsigned short* ar = Asm + (m * 16 + c0) * AS + g * 8;
        #pragma unroll
        for (int kt = 0; kt < KT; ++kt) {
            bf16x8 a = *(const bf16x8*)(ar + kt * 32);
            acc[m][0] = __builtin_amdgcn_mfma_f32_16x16x32_bf16(a, bfr[kt][0], acc[m][0], 0, 0, 0);
            acc[m][1] = __builtin_amdgcn_mfma_f32_16x16x32_bf16(a, bfr[kt][1], acc[m][1], 0, 0, 0);
        }
    }

    #pragma unroll
    for (int m = 0; m < 4; ++m) {
        #pragma unroll
        for (int r = 0; r < 4; ++r) {
            float h0v = acc[m][0][r] + bia[0];
            float h1v = acc[m][1][r] + bia[1];
            float s = h0v + h1v, q = h0v * h0v + h1v * h1v;
            #pragma unroll
            for (int mm = 1; mm < 16; mm <<= 1) {
                s += __shfl_xor(s, mm, 64);
                q += __shfl_xor(q, mm, 64);
            }
            if (c0 == 0) {
                int node = m * 16 + g * 4 + r;
                sP[node * 4 + w] = s;
                qP[node * 4 + w] = q;
            }
        }
    }
    __syncthreads();

    #pragma unroll
    for (int m = 0; m < 4; ++m) {
        #pragma unroll
        for (int r = 0; r < 4; ++r) {
            int node = m * 16 + g * 4 + r;
            float4 sv = *(const float4*)&sP[node * 4];
            float4 qv = *(const float4*)&qP[node * 4];
            float s = (sv.x + sv.y) + (sv.z + sv.w);
            float q = (qv.x + qv.y) + (qv.z + qv.w);
            float mu   = s * (1.f / 128.f);
            float var  = q * (1.f / 128.f) - mu * mu;
            float rinv = rsqrtf(var + LN_EPS);
            float h0v = acc[m][0][r] + bia[0];
            float h1v = acc[m][1][r] + bia[1];
            float v0 = fmaxf(0.f, (h0v - mu) * rinv * gam[0] + bet[0]);
            float v1 = fmaxf(0.f, (h1v - mu) * rinv * gam[1] + bet[1]);
            size_t gn = (size_t)(n0 + node);
            A1[gn * 256 + 128 + (2 * w) * 16 + c0]     = f2bf(v0);
            A1[gn * 256 + 128 + (2 * w + 1) * 16 + c0] = f2bf(v1);
        }
    }
}

// ---------------- layer1 GEMM (regB) + LN + ReLU + fused pooling ----------------
__global__ __launch_bounds__(256, 2) void gemm1_kernel(
    const unsigned short* __restrict__ A,
    const unsigned short* __restrict__ Wt,
    const float* __restrict__ bias, const float* __restrict__ gamma,
    const float* __restrict__ beta,
    const int* __restrict__ batch,
    float* __restrict__ psum, int* __restrict__ pmax)
{
    constexpr int K = 256, KT = K / 32, AS = K + 8, CPR = K / 8;
    __shared__ __align__(16) char smem[64 * AS * 2];   // Asm; aliased by Hs post-MFMA
    unsigned short* Asm = (unsigned short*)smem;
    float* Hs = (float*)smem;
    __shared__ __align__(16) float sP[64 * 4];
    __shared__ __align__(16) float qP[64 * 4];
    __shared__ int bS[64];

    const int tid = threadIdx.x;
    const int n0 = blockIdx.x * 64;

    if (tid < 64) {
        int gn = n0 + tid;
        bS[tid] = (gn < NN) ? batch[gn] : -1;
    }
    for (int i = tid; i < 64 * CPR; i += 256) {
        int node = i / CPR, c = i - node * CPR;
        uint4 v = *(const uint4*)(A + (size_t)(n0 + node) * K + c * 8);
        *(uint4*)(Asm + node * AS + c * 8) = v;
    }

    const int l = tid & 63, w = tid >> 6;
    const int g = l >> 4, c0 = l & 15;
    bf16x8 bfr[KT][2];
    #pragma unroll
    for (int j = 0; j < 2; ++j) {
        const unsigned short* bp = Wt + (size_t)((2 * w + j) * 16 + c0) * K + g * 8;
        #pragma unroll
        for (int kt = 0; kt < KT; ++kt)
            bfr[kt][j] = *(const bf16x8*)(bp + kt * 32);
    }
    float bia[2], gam[2], bet[2];
    #pragma unroll
    for (int j = 0; j < 2; ++j) {
        int col = (2 * w + j) * 16 + c0;
        bia[j] = bias[col]; gam[j] = gamma[col]; bet[j] = beta[col];
    }
    __syncthreads();

    f32x4 acc[4][2];
    #pragma unroll
    for (int m = 0; m < 4; ++m) {
        acc[m][0] = (f32x4){0.f, 0.f, 0.f, 0.f};
        acc[m][1] = (f32x4){0.f, 0.f, 0.f, 0.f};
    }
    #pragma unroll
    for (int m = 0; m < 4; ++m) {
        const unsigned short* ar = Asm + (m * 16 + c0) * AS + g * 8;
        #pragma unroll
        for (int kt = 0; kt < KT; ++kt) {
            bf16x8 a = *(const bf16x8*)(ar + kt * 32);
            acc[m][0] = __builtin_amdgcn_mfma_f32_16x16x32_bf16(a, bfr[kt][0], acc[m][0], 0, 0, 0);
            acc[m][1] = __builtin_amdgcn_mfma_f32_16x16x32_bf16(a, bfr[kt][1], acc[m][1], 0, 0, 0);
        }
    }

    // LN phase 1
    #pragma unroll
    for (int m = 0; m < 4; ++m) {
        #pragma unroll
        for (int r = 0; r < 4; ++r) {
            float h0v = acc[m][0][r] + bia[0];
            float h1v = acc[m][1][r] + bia[1];
            float s = h0v + h1v, q = h0v * h0v + h1v * h1v;
            #pragma unroll
            for (int mm = 1; mm < 16; mm <<= 1) {
                s += __shfl_xor(s, mm, 64);
                q += __shfl_xor(q, mm, 64);
            }
            if (c0 == 0) {
                int node = m * 16 + g * 4 + r;
                sP[node * 4 + w] = s;
                qP[node * 4 + w] = q;
            }
        }
    }
    __syncthreads();   // MFMA Asm reads complete; sP/qP visible

    // LN phase 2 + ReLU -> Hs (overwrites Asm region)
    #pragma unroll
    for (int m = 0; m < 4; ++m) {
        #pragma unroll
        for (int r = 0; r < 4; ++r) {
            int node = m * 16 + g * 4 + r;
            float4 sv = *(const float4*)&sP[node * 4];
            float4 qv = *(const float4*)&qP[node * 4];
            float s = (sv.x + sv.y) + (sv.z + sv.w);
            float q = (qv.x + qv.y) + (qv.z + qv.w);
            float mu   = s * (1.f / 128.f);
            float var  = q * (1.f / 128.f) - mu * mu;
            float rinv = rsqrtf(var + LN_EPS);
            float h0v = acc[m][0][r] + bia[0];
            float h1v = acc[m][1][r] + bia[1];
            float v0 = fmaxf(0.f, (h0v - mu) * rinv * gam[0] + bet[0]);
            float v1 = fmaxf(0.f, (h1v - mu) * rinv * gam[1] + bet[1]);
            Hs[node * 128 + (2 * w) * 16 + c0]     = v0;
            Hs[node * 128 + (2 * w + 1) * 16 + c0] = v1;
        }
    }
    __syncthreads();

    // fused pooling: 128 threads, one column each; sorted batch -> few flushes
    if (tid < 128) {
        int j = tid;
        int curg = -1; float s = 0.f, m = 0.f;
        #pragma unroll 4
        for (int n = 0; n < 64; ++n) {
            int gb = bS[n];
            if (gb < 0) break;
            if (gb != curg) {
                if (curg >= 0) {
                    atomicAdd(&psum[curg * 128 + j], s);
                    atomicMax(&pmax[curg * 128 + j], __float_as_int(m));
                }
                curg = gb; s = 0.f; m = 0.f;
            }
            float v = Hs[n * 128 + j];
            s += v; m = fmaxf(m, v);
        }
        if (curg >= 0) {
            atomicAdd(&psum[curg * 128 + j], s);
            atomicMax(&pmax[curg * 128 + j], __float_as_int(m));
        }
    }
}

// ---------------- final MLP (one block per graph; cnt via binary search) ----------------
__device__ __forceinline__ int lbound(const int* a, int n, int v) {
    int lo = 0, hi = n;
    while (lo < hi) { int mid = (lo + hi) >> 1; if (a[mid] < v) lo = mid + 1; else hi = mid; }
    return lo;
}

__global__ __launch_bounds__(64) void mlp_kernel(
    const float* __restrict__ psum, const int* __restrict__ pmax,
    const int* __restrict__ batch,
    const float* __restrict__ Wf0, const float* __restrict__ bf0,
    const float* __restrict__ Wf1, const float* __restrict__ bf1,
    const float* __restrict__ Wf2, const float* __restrict__ bf2,
    float* __restrict__ out)
{
    __shared__ float z[256];
    __shared__ float t1[50];
    __shared__ float t2[50];
    __shared__ int cS;
    int g = blockIdx.x, t = threadIdx.x;
    if (t == 0) cS = lbound(batch, NN, g + 1) - lbound(batch, NN, g);
    __syncthreads();
    int c = cS;
    float ic = 1.0f / (float)(c > 1 ? c : 1);
    for (int j = t; j < 128; j += 64) {
        z[j]       = psum[g * 128 + j] * ic;
        z[128 + j] = __int_as_float(pmax[g * 128 + j]);
    }
    __syncthreads();
    if (t < 50) {
        float a = bf0[t];
        for (int k = 0; k < 256; ++k) a = fmaf(z[k], Wf0[k * 50 + t], a);
        t1[t] = fmaxf(a, 0.0f);
    }
    __syncthreads();
    if (t < 50) {
        float a = bf1[t];
        for (int k = 0; k < 50; ++k) a = fmaf(t1[k], Wf1[k * 50 + t], a);
        t2[t] = fmaxf(a, 0.0f);
    }
    __syncthreads();
    if (t < 10) {
        float a = bf2[t];
        for (int k = 0; k < 50; ++k) a = fmaf(t2[k], Wf2[k * 10 + t], a);
        out[g * 10 + t] = fmaxf(a, 0.0f);
    }
}

// ---------------- launcher ----------------
extern "C" void kernel_launch(void* const* d_in, const int* in_sizes, int n_in,
                              void* d_out, int out_size, void* d_ws, size_t ws_size,
                              hipStream_t stream)
{
    const float* x     = (const float*)d_in[0];
    const float* xdims = (const float*)d_in[1];
    const int*   stt   = (const int*)d_in[2];
    const int*   ei    = (const int*)d_in[3];
    const int*   batch = (const int*)d_in[4];
    const float* emb   = (const float*)d_in[5];
    const float* Wl0   = (const float*)d_in[6];
    const float* bl0   = (const float*)d_in[7];
    const float* Wr0   = (const float*)d_in[8];
    const float* g0    = (const float*)d_in[9];
    const float* bn0   = (const float*)d_in[10];
    const float* Wl1   = (const float*)d_in[11];
    const float* bl1   = (const float*)d_in[12];
    const float* Wr1   = (const float*)d_in[13];
    const float* g1    = (const float*)d_in[14];
    const float* bn1   = (const float*)d_in[15];
    const float* Wf0   = (const float*)d_in[16];
    const float* bf0   = (const float*)d_in[17];
    const float* Wf1   = (const float*)d_in[18];
    const float* bf1   = (const float*)d_in[19];
    const float* Wf2   = (const float*)d_in[20];
    const float* bf2   = (const float*)d_in[21];

    char* w = (char*)d_ws;
    unsigned short* A0  = (unsigned short*)w; w += (size_t)NP * 160 * 2;
    unsigned short* A1  = (unsigned short*)w; w += (size_t)NP * 256 * 2;
    unsigned short* Wt0 = (unsigned short*)w; w += (size_t)128 * 160 * 2;
    unsigned short* Wt1 = (unsigned short*)w; w += (size_t)128 * 256 * 2;
    int*   csr    = (int*)w;   w += (size_t)EE * 4;
    int*   offs   = (int*)w;   w += (size_t)NN * 4;
    int*   bsum   = (int*)w;   w += 1024;
    // zeroed region (one memset):
    char* zbeg = w;
    int*   deg  = (int*)w;   w += (size_t)NP * 4;
    int*   cur  = (int*)w;   w += (size_t)NN * 4;
    float* psum = (float*)w; w += (size_t)GG * 128 * 4;
    int*   pmax = (int*)w;   w += (size_t)GG * 128 * 4;
    size_t zsz = (size_t)(w - zbeg);

    hipMemsetAsync(zbeg, 0, zsz, stream);

    prep_kernel<<<(PREP_TOT + 255) / 256, 256, 0, stream>>>(
        x, xdims, stt, emb, ei, Wl0, Wr0, Wl1, Wr1, A0, Wt0, Wt1, deg);

    int nb = (NN + 2047) / 2048;   // 49
    scan1_kernel<<<nb, 256, 0, stream>>>(deg, offs, bsum);
    scan2_kernel<<<1, 64, 0, stream>>>(bsum, nb);
    fill_csr_kernel<<<(EE + 255) / 256, 256, 0, stream>>>(ei, cur, offs, bsum, csr);

    agg0_kernel<<<NP / 16, 256, 0, stream>>>(A0, csr, offs, bsum, deg);
    gemm0_kernel<<<NP / 64, 256, 0, stream>>>(A0, Wt0, bl0, g0, bn0, A1);
    agg1_kernel<<<NP / 16, 256, 0, stream>>>(A1, csr, offs, bsum, deg);
    gemm1_kernel<<<NP / 64, 256, 0, stream>>>(A1, Wt1, bl1, g1, bn1, batch, psum, pmax);

    mlp_kernel<<<GG, 64, 0, stream>>>(psum, pmax, batch, Wf0, bf0, Wf1, bf1, Wf2, bf2,
                                      (float*)d_out);
}

// Round 6
// 310.893 us; speedup vs baseline: 2.5747x; 1.0169x over previous
//
#include <hip/hip_runtime.h>

#define NN 100000
#define NP 100096          // padded to multiple of 64 (and 32)
#define EE 600000
#define GG 512
#define LN_EPS 1e-5f

typedef __attribute__((ext_vector_type(8))) __bf16 bf16x8;
typedef __attribute__((ext_vector_type(4))) float f32x4;

__device__ __forceinline__ unsigned short f2bf(float f) {
    unsigned int u = __float_as_uint(f);
    u = (u + 0x7fffu + ((u >> 16) & 1u)) >> 16;
    return (unsigned short)u;
}
__device__ __forceinline__ unsigned int pack2(float a, float b) {
    return (unsigned int)f2bf(a) | ((unsigned int)f2bf(b) << 16);
}
__device__ __forceinline__ void acc8(float* s, uint4 v) {
    s[0] += __uint_as_float(v.x << 16);
    s[1] += __uint_as_float(v.x & 0xffff0000u);
    s[2] += __uint_as_float(v.y << 16);
    s[3] += __uint_as_float(v.y & 0xffff0000u);
    s[4] += __uint_as_float(v.z << 16);
    s[5] += __uint_as_float(v.z & 0xffff0000u);
    s[6] += __uint_as_float(v.w << 16);
    s[7] += __uint_as_float(v.w & 0xffff0000u);
}

// ---------------- merged prep: assemble A0 root cols + wtprep both layers + degree count ----
#define PREP_A (NP * 10)
#define PREP_W0 (128 * 160)
#define PREP_W1 (128 * 256)
#define PREP_TOT (PREP_A + PREP_W0 + PREP_W1 + EE)

__global__ __launch_bounds__(256) void prep_kernel(
    const float* __restrict__ x, const float* __restrict__ xdims,
    const int* __restrict__ stt, const float* __restrict__ emb,
    const int* __restrict__ ei,
    const float* __restrict__ Wl0, const float* __restrict__ Wr0,
    const float* __restrict__ Wl1, const float* __restrict__ Wr1,
    unsigned short* __restrict__ A0,
    unsigned short* __restrict__ Wt0, unsigned short* __restrict__ Wt1,
    int* __restrict__ deg)
{
    int idx = blockIdx.x * 256 + threadIdx.x;
    if (idx < PREP_A) {
        int node = idx / 10;
        int c8 = (idx - node * 10) * 8;   // feature base 0..72
        unsigned short vals[8];
        if (node < NN) {
            int st = stt[node];
            #pragma unroll
            for (int i = 0; i < 8; ++i) {
                int f = c8 + i;
                float v = 0.f;
                if (f < 60)      v = x[node * 60 + f];
                else if (f < 62) v = xdims[node * 2 + (f - 60)];
                else if (f < 74) v = emb[st * 12 + (f - 62)];
                vals[i] = f2bf(v);
            }
        } else {
            #pragma unroll
            for (int i = 0; i < 8; ++i) vals[i] = 0;
        }
        uint4 o;
        o.x = (unsigned)vals[0] | ((unsigned)vals[1] << 16);
        o.y = (unsigned)vals[2] | ((unsigned)vals[3] << 16);
        o.z = (unsigned)vals[4] | ((unsigned)vals[5] << 16);
        o.w = (unsigned)vals[6] | ((unsigned)vals[7] << 16);
        *(uint4*)(A0 + (size_t)node * 160 + 80 + c8) = o;
    } else if (idx < PREP_A + PREP_W0) {
        int j = idx - PREP_A;
        int n = j / 160, k = j - n * 160;
        float v = 0.f;
        if (k < 74)                  v = Wl0[k * 128 + n];
        else if (k >= 80 && k < 154) v = Wr0[(k - 80) * 128 + n];
        Wt0[(size_t)n * 160 + k] = f2bf(v);
    } else if (idx < PREP_A + PREP_W0 + PREP_W1) {
        int j = idx - PREP_A - PREP_W0;
        int n = j >> 8, k = j & 255;
        float v = (k < 128) ? Wl1[k * 128 + n] : Wr1[(k - 128) * 128 + n];
        Wt1[(size_t)n * 256 + k] = f2bf(v);
    } else if (idx < PREP_TOT) {
        int e = idx - PREP_A - PREP_W0 - PREP_W1;
        atomicAdd(&deg[ei[EE + e]], 1);
    }
}

// ---------------- exclusive scan of deg -> offs (local) + bsum ----------------
__global__ __launch_bounds__(256) void scan1_kernel(
    const int* __restrict__ deg, int* __restrict__ offs, int* __restrict__ bsum)
{
    __shared__ int ts[256];
    int t = threadIdx.x;
    int base = blockIdx.x * 2048 + t * 8;
    int d[8];
    if (base + 8 <= NN) {
        int4 a = *(const int4*)&deg[base];
        int4 b = *(const int4*)&deg[base + 4];
        d[0]=a.x; d[1]=a.y; d[2]=a.z; d[3]=a.w;
        d[4]=b.x; d[5]=b.y; d[6]=b.z; d[7]=b.w;
    } else {
        #pragma unroll
        for (int i = 0; i < 8; ++i) d[i] = (base + i < NN) ? deg[base + i] : 0;
    }
    int e[8]; int run = 0;
    #pragma unroll
    for (int i = 0; i < 8; ++i) { e[i] = run; run += d[i]; }
    ts[t] = run;
    int tot = run;
    __syncthreads();
    for (int off = 1; off < 256; off <<= 1) {
        int u = (t >= off) ? ts[t - off] : 0;
        __syncthreads();
        ts[t] += u;
        __syncthreads();
    }
    int pre = ts[t] - tot;
    #pragma unroll
    for (int i = 0; i < 8; ++i) if (base + i < NN) offs[base + i] = e[i] + pre;
    if (t == 255) bsum[blockIdx.x] = ts[255];
}

__global__ void scan2_kernel(int* __restrict__ bsum, int nb)
{
    int t = threadIdx.x;   // one wave
    int v = (t < nb) ? bsum[t] : 0;
    int inc = v;
    for (int off = 1; off < 64; off <<= 1) {
        int u = __shfl_up(inc, off, 64);
        if (t >= off) inc += u;
    }
    if (t < nb) bsum[t] = inc - v;   // exclusive
}

// ---------------- CSR fill (bsum folded in) ----------------
__global__ __launch_bounds__(256) void fill_csr_kernel(
    const int* __restrict__ ei, int* __restrict__ cur,
    const int* __restrict__ offs, const int* __restrict__ bsum,
    int* __restrict__ csr)
{
    int e = blockIdx.x * 256 + threadIdx.x;
    if (e >= EE) return;
    int d = ei[EE + e];
    int p = offs[d] + bsum[d >> 11] + atomicAdd(&cur[d], 1);
    csr[p] = ei[e];
}

// ---------------- agg0: gather A0 cols 80..159 -> mean into cols 0..79 ----------------
__global__ __launch_bounds__(256) void agg0_kernel(
    unsigned short* __restrict__ A0, const int* __restrict__ csr,
    const int* __restrict__ offs, const int* __restrict__ bsum,
    const int* __restrict__ deg)
{
    int node = blockIdx.x * 16 + (threadIdx.x >> 4);
    int lane = threadIdx.x & 15;
    if (node >= NP || lane >= 10) return;
    int d = 0, st = 0;
    if (node < NN) { d = deg[node]; st = offs[node] + bsum[node >> 11]; }
    float iv = 1.0f / (float)(d > 1 ? d : 1);
    float s[8];
    #pragma unroll
    for (int i = 0; i < 8; ++i) s[i] = 0.f;
    int e = 0;
    for (; e + 4 <= d; e += 4) {
        int i0 = csr[st + e],     i1 = csr[st + e + 1];
        int i2 = csr[st + e + 2], i3 = csr[st + e + 3];
        uint4 v0 = *(const uint4*)(A0 + (size_t)i0 * 160 + 80 + lane * 8);
        uint4 v1 = *(const uint4*)(A0 + (size_t)i1 * 160 + 80 + lane * 8);
        uint4 v2 = *(const uint4*)(A0 + (size_t)i2 * 160 + 80 + lane * 8);
        uint4 v3 = *(const uint4*)(A0 + (size_t)i3 * 160 + 80 + lane * 8);
        acc8(s, v0); acc8(s, v1); acc8(s, v2); acc8(s, v3);
    }
    for (; e < d; ++e) {
        int i0 = csr[st + e];
        uint4 v0 = *(const uint4*)(A0 + (size_t)i0 * 160 + 80 + lane * 8);
        acc8(s, v0);
    }
    uint4 o;
    o.x = pack2(s[0] * iv, s[1] * iv);
    o.y = pack2(s[2] * iv, s[3] * iv);
    o.z = pack2(s[4] * iv, s[5] * iv);
    o.w = pack2(s[6] * iv, s[7] * iv);
    *(uint4*)(A0 + (size_t)node * 160 + lane * 8) = o;
}

// ---------------- agg1: gather A1 cols 128..255 -> mean into cols 0..127 ----------------
__global__ __launch_bounds__(256) void agg1_kernel(
    unsigned short* __restrict__ A1, const int* __restrict__ csr,
    const int* __restrict__ offs, const int* __restrict__ bsum,
    const int* __restrict__ deg)
{
    int node = blockIdx.x * 16 + (threadIdx.x >> 4);
    int lane = threadIdx.x & 15;
    if (node >= NP) return;
    int d = 0, st = 0;
    if (node < NN) { d = deg[node]; st = offs[node] + bsum[node >> 11]; }
    float iv = 1.0f / (float)(d > 1 ? d : 1);
    float s[8];
    #pragma unroll
    for (int i = 0; i < 8; ++i) s[i] = 0.f;
    int e = 0;
    for (; e + 4 <= d; e += 4) {
        int i0 = csr[st + e],     i1 = csr[st + e + 1];
        int i2 = csr[st + e + 2], i3 = csr[st + e + 3];
        uint4 v0 = *(const uint4*)(A1 + (size_t)i0 * 256 + 128 + lane * 8);
        uint4 v1 = *(const uint4*)(A1 + (size_t)i1 * 256 + 128 + lane * 8);
        uint4 v2 = *(const uint4*)(A1 + (size_t)i2 * 256 + 128 + lane * 8);
        uint4 v3 = *(const uint4*)(A1 + (size_t)i3 * 256 + 128 + lane * 8);
        acc8(s, v0); acc8(s, v1); acc8(s, v2); acc8(s, v3);
    }
    for (; e < d; ++e) {
        int i0 = csr[st + e];
        uint4 v0 = *(const uint4*)(A1 + (size_t)i0 * 256 + 128 + lane * 8);
        acc8(s, v0);
    }
    uint4 o;
    o.x = pack2(s[0] * iv, s[1] * iv);
    o.y = pack2(s[2] * iv, s[3] * iv);
    o.z = pack2(s[4] * iv, s[5] * iv);
    o.w = pack2(s[6] * iv, s[7] * iv);
    *(uint4*)(A1 + (size_t)node * 256 + 128 - 128 + lane * 8) = o;
}

// ---------------- GEMM (32-node tile, kt-outer B loads) + LN + ReLU [+ pooling] ---------
// block = 256 thr = 4 waves; 32 nodes x 128 cols per block.
// Wave w covers cols [32w, 32w+32) (nt = 2w, 2w+1); m-tiles 0..1 (16 nodes each).
// kt-outer: B fragments for tile kt loaded once (2 loads), consumed by 4 MFMAs.
// A-frag:  node = m*16 + (lane&15), k = (lane>>4)*8 + j   [m120]
// C/D:     col-lane = lane&15, row = (lane>>4)*4 + reg    [m89]
template<int K, bool POOL>
__global__ __launch_bounds__(256, 4) void gemm_kernel(
    const unsigned short* __restrict__ A,
    const unsigned short* __restrict__ Wt,
    const float* __restrict__ bias, const float* __restrict__ gamma,
    const float* __restrict__ beta,
    unsigned short* __restrict__ outB,            // !POOL: A1 (+128 col offset)
    const int* __restrict__ batch,                // POOL only
    float* __restrict__ psum, int* __restrict__ pmax)
{
    constexpr int KT = K / 32, AS = K + 8, CPR = K / 8;
    constexpr int SMEM = (32 * AS * 2 > 32 * 128 * 4) ? 32 * AS * 2 : 32 * 128 * 4;
    __shared__ __align__(16) char smem[SMEM];     // Asm; aliased by Hs post-MFMA (POOL)
    unsigned short* Asm = (unsigned short*)smem;
    float* Hs = (float*)smem;
    __shared__ __align__(16) float sP[32 * 4];
    __shared__ __align__(16) float qP[32 * 4];
    __shared__ int bS[32];

    const int tid = threadIdx.x;
    const int n0 = blockIdx.x * 32;

    if (POOL && tid < 32) {
        int gn = n0 + tid;
        bS[tid] = (gn < NN) ? batch[gn] : -1;
    }
    for (int i = tid; i < 32 * CPR; i += 256) {
        int node = i / CPR, c = i - node * CPR;
        uint4 v = *(const uint4*)(A + (size_t)(n0 + node) * K + c * 8);
        *(uint4*)(Asm + node * AS + c * 8) = v;
    }

    const int l = tid & 63, w = tid >> 6;
    const int g = l >> 4, c0 = l & 15;
    float bia[2], gam[2], bet[2];
    #pragma unroll
    for (int j = 0; j < 2; ++j) {
        int col = (2 * w + j) * 16 + c0;
        bia[j] = bias[col]; gam[j] = gamma[col]; bet[j] = beta[col];
    }
    const unsigned short* bp0 = Wt + (size_t)((2 * w + 0) * 16 + c0) * K + g * 8;
    const unsigned short* bp1 = Wt + (size_t)((2 * w + 1) * 16 + c0) * K + g * 8;
    const unsigned short* ar0 = Asm + (0 * 16 + c0) * AS + g * 8;
    const unsigned short* ar1 = Asm + (1 * 16 + c0) * AS + g * 8;
    __syncthreads();

    f32x4 acc[2][2];
    acc[0][0] = (f32x4){0.f,0.f,0.f,0.f}; acc[0][1] = (f32x4){0.f,0.f,0.f,0.f};
    acc[1][0] = (f32x4){0.f,0.f,0.f,0.f}; acc[1][1] = (f32x4){0.f,0.f,0.f,0.f};

    #pragma unroll
    for (int kt = 0; kt < KT; ++kt) {
        bf16x8 b0 = *(const bf16x8*)(bp0 + kt * 32);
        bf16x8 b1 = *(const bf16x8*)(bp1 + kt * 32);
        bf16x8 a0 = *(const bf16x8*)(ar0 + kt * 32);
        bf16x8 a1 = *(const bf16x8*)(ar1 + kt * 32);
        acc[0][0] = __builtin_amdgcn_mfma_f32_16x16x32_bf16(a0, b0, acc[0][0], 0, 0, 0);
        acc[0][1] = __builtin_amdgcn_mfma_f32_16x16x32_bf16(a0, b1, acc[0][1], 0, 0, 0);
        acc[1][0] = __builtin_amdgcn_mfma_f32_16x16x32_bf16(a1, b0, acc[1][0], 0, 0, 0);
        acc[1][1] = __builtin_amdgcn_mfma_f32_16x16x32_bf16(a1, b1, acc[1][1], 0, 0, 0);
    }

    // LN phase 1: per-wave partials over this wave's 32 cols
    #pragma unroll
    for (int m = 0; m < 2; ++m) {
        #pragma unroll
        for (int r = 0; r < 4; ++r) {
            float h0v = acc[m][0][r] + bia[0];
            float h1v = acc[m][1][r] + bia[1];
            float s = h0v + h1v, q = h0v * h0v + h1v * h1v;
            #pragma unroll
            for (int mm = 1; mm < 16; mm <<= 1) {
                s += __shfl_xor(s, mm, 64);
                q += __shfl_xor(q, mm, 64);
            }
            if (c0 == 0) {
                int node = m * 16 + g * 4 + r;
                sP[node * 4 + w] = s;
                qP[node * 4 + w] = q;
            }
        }
    }
    __syncthreads();   // MFMA Asm reads done; sP/qP visible

    // LN phase 2 + ReLU + store
    #pragma unroll
    for (int m = 0; m < 2; ++m) {
        #pragma unroll
        for (int r = 0; r < 4; ++r) {
            int node = m * 16 + g * 4 + r;
            float4 sv = *(const float4*)&sP[node * 4];
            float4 qv = *(const float4*)&qP[node * 4];
            float s = (sv.x + sv.y) + (sv.z + sv.w);
            float q = (qv.x + qv.y) + (qv.z + qv.w);
            float mu   = s * (1.f / 128.f);
            float var  = q * (1.f / 128.f) - mu * mu;
            float rinv = rsqrtf(var + LN_EPS);
            float h0v = acc[m][0][r] + bia[0];
            float h1v = acc[m][1][r] + bia[1];
            float v0 = fmaxf(0.f, (h0v - mu) * rinv * gam[0] + bet[0]);
            float v1 = fmaxf(0.f, (h1v - mu) * rinv * gam[1] + bet[1]);
            if (POOL) {
                Hs[node * 128 + (2 * w) * 16 + c0]     = v0;
                Hs[node * 128 + (2 * w + 1) * 16 + c0] = v1;
            } else {
                size_t gn = (size_t)(n0 + node);
                outB[gn * 256 + 128 + (2 * w) * 16 + c0]     = f2bf(v0);
                outB[gn * 256 + 128 + (2 * w + 1) * 16 + c0] = f2bf(v1);
            }
        }
    }
    if (!POOL) return;
    __syncthreads();

    // fused pooling: 128 threads, one column each; sorted batch -> few flushes
    if (tid < 128) {
        int j = tid;
        int curg = -1; float s = 0.f, m = 0.f;
        #pragma unroll 4
        for (int n = 0; n < 32; ++n) {
            int gb = bS[n];
            if (gb < 0) break;
            if (gb != curg) {
                if (curg >= 0) {
                    atomicAdd(&psum[curg * 128 + j], s);
                    atomicMax(&pmax[curg * 128 + j], __float_as_int(m));
                }
                curg = gb; s = 0.f; m = 0.f;
            }
            float v = Hs[n * 128 + j];
            s += v; m = fmaxf(m, v);
        }
        if (curg >= 0) {
            atomicAdd(&psum[curg * 128 + j], s);
            atomicMax(&pmax[curg * 128 + j], __float_as_int(m));
        }
    }
}

// ---------------- final MLP (one block per graph; cnt via binary search) ----------------
__device__ __forceinline__ int lbound(const int* a, int n, int v) {
    int lo = 0, hi = n;
    while (lo < hi) { int mid = (lo + hi) >> 1; if (a[mid] < v) lo = mid + 1; else hi = mid; }
    return lo;
}

__global__ __launch_bounds__(64) void mlp_kernel(
    const float* __restrict__ psum, const int* __restrict__ pmax,
    const int* __restrict__ batch,
    const float* __restrict__ Wf0, const float* __restrict__ bf0,
    const float* __restrict__ Wf1, const float* __restrict__ bf1,
    const float* __restrict__ Wf2, const float* __restrict__ bf2,
    float* __restrict__ out)
{
    __shared__ float z[256];
    __shared__ float t1[50];
    __shared__ float t2[50];
    __shared__ int cS;
    int g = blockIdx.x, t = threadIdx.x;
    if (t == 0) cS = lbound(batch, NN, g + 1) - lbound(batch, NN, g);
    __syncthreads();
    int c = cS;
    float ic = 1.0f / (float)(c > 1 ? c : 1);
    for (int j = t; j < 128; j += 64) {
        z[j]       = psum[g * 128 + j] * ic;
        z[128 + j] = __int_as_float(pmax[g * 128 + j]);
    }
    __syncthreads();
    if (t < 50) {
        float a = bf0[t];
        for (int k = 0; k < 256; ++k) a = fmaf(z[k], Wf0[k * 50 + t], a);
        t1[t] = fmaxf(a, 0.0f);
    }
    __syncthreads();
    if (t < 50) {
        float a = bf1[t];
        for (int k = 0; k < 50; ++k) a = fmaf(t1[k], Wf1[k * 50 + t], a);
        t2[t] = fmaxf(a, 0.0f);
    }
    __syncthreads();
    if (t < 10) {
        float a = bf2[t];
        for (int k = 0; k < 50; ++k) a = fmaf(t2[k], Wf2[k * 10 + t], a);
        out[g * 10 + t] = fmaxf(a, 0.0f);
    }
}

// ---------------- launcher ----------------
extern "C" void kernel_launch(void* const* d_in, const int* in_sizes, int n_in,
                              void* d_out, int out_size, void* d_ws, size_t ws_size,
                              hipStream_t stream)
{
    const float* x     = (const float*)d_in[0];
    const float* xdims = (const float*)d_in[1];
    const int*   stt   = (const int*)d_in[2];
    const int*   ei    = (const int*)d_in[3];
    const int*   batch = (const int*)d_in[4];
    const float* emb   = (const float*)d_in[5];
    const float* Wl0   = (const float*)d_in[6];
    const float* bl0   = (const float*)d_in[7];
    const float* Wr0   = (const float*)d_in[8];
    const float* g0    = (const float*)d_in[9];
    const float* bn0   = (const float*)d_in[10];
    const float* Wl1   = (const float*)d_in[11];
    const float* bl1   = (const float*)d_in[12];
    const float* Wr1   = (const float*)d_in[13];
    const float* g1    = (const float*)d_in[14];
    const float* bn1   = (const float*)d_in[15];
    const float* Wf0   = (const float*)d_in[16];
    const float* bf0   = (const float*)d_in[17];
    const float* Wf1   = (const float*)d_in[18];
    const float* bf1   = (const float*)d_in[19];
    const float* Wf2   = (const float*)d_in[20];
    const float* bf2   = (const float*)d_in[21];

    char* w = (char*)d_ws;
    unsigned short* A0  = (unsigned short*)w; w += (size_t)NP * 160 * 2;
    unsigned short* A1  = (unsigned short*)w; w += (size_t)NP * 256 * 2;
    unsigned short* Wt0 = (unsigned short*)w; w += (size_t)128 * 160 * 2;
    unsigned short* Wt1 = (unsigned short*)w; w += (size_t)128 * 256 * 2;
    int*   csr    = (int*)w;   w += (size_t)EE * 4;
    int*   offs   = (int*)w;   w += (size_t)NN * 4;
    int*   bsum   = (int*)w;   w += 1024;
    // zeroed region (one memset):
    char* zbeg = w;
    int*   deg  = (int*)w;   w += (size_t)NP * 4;
    int*   cur  = (int*)w;   w += (size_t)NN * 4;
    float* psum = (float*)w; w += (size_t)GG * 128 * 4;
    int*   pmax = (int*)w;   w += (size_t)GG * 128 * 4;
    size_t zsz = (size_t)(w - zbeg);

    hipMemsetAsync(zbeg, 0, zsz, stream);

    prep_kernel<<<(PREP_TOT + 255) / 256, 256, 0, stream>>>(
        x, xdims, stt, emb, ei, Wl0, Wr0, Wl1, Wr1, A0, Wt0, Wt1, deg);

    int nb = (NN + 2047) / 2048;   // 49
    scan1_kernel<<<nb, 256, 0, stream>>>(deg, offs, bsum);
    scan2_kernel<<<1, 64, 0, stream>>>(bsum, nb);
    fill_csr_kernel<<<(EE + 255) / 256, 256, 0, stream>>>(ei, cur, offs, bsum, csr);

    agg0_kernel<<<NP / 16, 256, 0, stream>>>(A0, csr, offs, bsum, deg);
    gemm_kernel<160, false><<<NP / 32, 256, 0, stream>>>(
        A0, Wt0, bl0, g0, bn0, A1, nullptr, nullptr, nullptr);
    agg1_kernel<<<NP / 16, 256, 0, stream>>>(A1, csr, offs, bsum, deg);
    gemm_kernel<256, true><<<NP / 32, 256, 0, stream>>>(
        A1, Wt1, bl1, g1, bn1, nullptr, batch, psum, pmax);

    mlp_kernel<<<GG, 64, 0, stream>>>(psum, pmax, batch, Wf0, bf0, Wf1, bf1, Wf2, bf2,
                                      (float*)d_out);
}